// Round 12
// baseline (622.240 us; speedup 1.0000x reference)
//
#include <hip/hip_runtime.h>

typedef __attribute__((ext_vector_type(8))) short bfrag;   // 8 x bf16
typedef __attribute__((ext_vector_type(4))) float f4;

#define MFMA(a,b,c) __builtin_amdgcn_mfma_f32_16x16x32_bf16(a,b,c,0,0,0)

__device__ __forceinline__ unsigned short f2b(float x){
  union { float f; unsigned int u; } v; v.f = x;
  unsigned int r = v.u + 0x7fffu + ((v.u >> 16) & 1u);
  return (unsigned short)(r >> 16);
}
__device__ __forceinline__ float b2f(unsigned short h){
  union { unsigned int u; float f; } v; v.u = ((unsigned int)h) << 16;
  return v.f;
}

// ---------------- merged prep kernel (weights + gathers + output copy) ----------------
__global__ __launch_bounds__(256) void k_prep(
    const float* __restrict__ qkv_w, const float* __restrict__ proj_w,
    const float* __restrict__ proj_b, const float* __restrict__ fuse_w,
    const float* __restrict__ fuse_b,
    const float* __restrict__ wt0,
    const float* __restrict__ wt1, const float* __restrict__ sk0w,
    const float* __restrict__ wi0, const float* __restrict__ bi0,
    const float* __restrict__ wj0, const float* __restrict__ bj0,
    const float* __restrict__ wi1, const float* __restrict__ bi1,
    const float* __restrict__ wj1, const float* __restrict__ bj1,
    const float* __restrict__ attn0, const float* __restrict__ attn1,
    const float* __restrict__ bt0, const float* __restrict__ bt1,
    const float* __restrict__ sk0b,
    const float* __restrict__ embed, const int* __restrict__ ids,
    unsigned short* __restrict__ BtQKV, unsigned short* __restrict__ BtW2,
    unsigned short* __restrict__ BtT0, unsigned short* __restrict__ BtT1,
    float* __restrict__ biasW2,
    float* __restrict__ biasT0, float* __restrict__ biasT1,
    float* __restrict__ wsum, float* __restrict__ Ei,
    float* __restrict__ out)
{
  int b = blockIdx.x, t = threadIdx.x;
  if (b < 1152) {            // QKV weight rows 128..383, transpose to [1152][256]
    int idx = b*256 + t; int k = idx/1152, n = idx - k*1152;
    BtQKV[(size_t)n*256 + k] = f2b(qkv_w[128*1152 + idx]);
  } else if (b < 1536) {     // W2 = proj_w @ fuse_w  -> Bt layout [256][384]
    int k = b - 1152;        // 0..383
    float s = 0.f;
    for (int j = 0; j < 384; ++j) s += proj_w[(size_t)k*384 + j] * fuse_w[(size_t)j*256 + t];
    BtW2[(size_t)t*384 + k] = f2b(s);
  } else if (b == 1536) {    // bias2 = proj_b @ fuse_w + fuse_b
    float s = fuse_b[t];
    for (int j = 0; j < 384; ++j) s += proj_b[j] * fuse_w[(size_t)j*256 + t];
    biasW2[t] = s;
  } else if (b < 2049) {     // wt0 256x512
    int idx = (b-1537)*256 + t; int k = idx/512, n = idx - k*512;
    BtT0[(size_t)n*256 + k] = f2b(wt0[idx]);
  } else if (b < 2305) {     // wt1 128x512
    int idx = (b-2049)*256 + t; int k = idx/512, n = idx - k*512;
    BtT1[(size_t)n*128 + k] = f2b(wt1[idx]);
  } else if (b < 2369) {     // sk0w 128x128 -> rows 520..647 of BtT1
    int idx = (b-2305)*256 + t; int k = idx/128, n = idx - k*128;
    BtT1[(size_t)(520+n)*128 + k] = f2b(sk0w[idx]);
  } else if (b < 2373) {     // attnred wi0 (K=256) -> BtT0 rows 512..515
    int idx = (b-2369)*256 + t;
    int h = idx >> 8, k = idx & 255;
    float s = 0.f;
    for (int d = 0; d < 128; ++d) s += wi0[(size_t)k*512 + h*128 + d] * attn0[h*128 + d];
    BtT0[(size_t)(512 + h)*256 + k] = f2b(s);
    if (idx < 4) {
      float sb = 0.f;
      for (int d = 0; d < 128; ++d) sb += bi0[idx*128 + d] * attn0[idx*128 + d];
      biasT0[512 + idx] = sb;
    }
  } else if (b < 2377) {     // attnred wj0 -> BtT0 rows 516..519
    int idx = (b-2373)*256 + t;
    int h = idx >> 8, k = idx & 255;
    float s = 0.f;
    for (int d = 0; d < 128; ++d) s += wj0[(size_t)k*512 + h*128 + d] * attn0[h*128 + d];
    BtT0[(size_t)(516 + h)*256 + k] = f2b(s);
    if (idx < 4) {
      float sb = 0.f;
      for (int d = 0; d < 128; ++d) sb += bj0[idx*128 + d] * attn0[idx*128 + d];
      biasT0[516 + idx] = sb;
    }
  } else if (b < 2379) {     // attnred wi1 (K=128) -> BtT1 rows 512..515
    int idx = (b-2377)*256 + t;
    int h = idx >> 7, k = idx & 127;
    float s = 0.f;
    for (int d = 0; d < 128; ++d) s += wi1[(size_t)k*512 + h*128 + d] * attn1[h*128 + d];
    BtT1[(size_t)(512 + h)*128 + k] = f2b(s);
    if (idx < 4) {
      float sb = 0.f;
      for (int d = 0; d < 128; ++d) sb += bi1[idx*128 + d] * attn1[idx*128 + d];
      biasT1[512 + idx] = sb;
    }
  } else if (b < 2381) {     // attnred wj1 -> BtT1 rows 516..519
    int idx = (b-2379)*256 + t;
    int h = idx >> 7, k = idx & 127;
    float s = 0.f;
    for (int d = 0; d < 128; ++d) s += wj1[(size_t)k*512 + h*128 + d] * attn1[h*128 + d];
    BtT1[(size_t)(516 + h)*128 + k] = f2b(s);
    if (idx < 4) {
      float sb = 0.f;
      for (int d = 0; d < 128; ++d) sb += bj1[idx*128 + d] * attn1[idx*128 + d];
      biasT1[516 + idx] = sb;
    }
  } else if (b < 2383) {     // copy bt0 -> biasT0[0..511]
    int idx = (b-2381)*256 + t; biasT0[idx] = bt0[idx];
  } else if (b < 2385) {     // copy bt1 -> biasT1[0..511]
    int idx = (b-2383)*256 + t; biasT1[idx] = bt1[idx];
  } else if (b == 2385) {    // copy sk0b -> biasT1[520..647]
    if (t < 128) biasT1[520 + t] = sk0b[t];
  } else if (b < 2391) {     // wsum
    int n = (b-2386)*256 + t;
    if (n < 1152) {
      float s = 0.f;
      for (int k = 0; k < 128; ++k) s += qkv_w[(size_t)k*1152 + n];
      wsum[n] = s;
    }
  } else if (b < 4439) {     // gather Ei (float4): 524288 elems
    int idx = (b-2391)*256 + t;
    int n = idx >> 6, c4 = idx & 63;
    reinterpret_cast<float4*>(Ei)[idx] =
        reinterpret_cast<const float4*>(embed + (size_t)ids[n]*256)[c4];
  } else {                   // output copy: embed -> out[1048576..], ids -> tail
    int i = (b-4439)*256 + t;
    if (i < 3200000)
      reinterpret_cast<float4*>(out)[262144 + i] = reinterpret_cast<const float4*>(embed)[i];
    if (i < 8192) out[13848576 + i] = (float)ids[i];
  }
}

// ---------------- CSR build ----------------
__global__ void k_deg(const int* __restrict__ ei, int* __restrict__ deg){
  int e = blockIdx.x*256 + threadIdx.x; if (e >= 131072) return;
  atomicAdd(&deg[ei[131072 + e]], 1);
}

__global__ __launch_bounds__(1024) void k_scan(const int* __restrict__ deg,
                                               int* __restrict__ off, int* __restrict__ cursor){
  int t = threadIdx.x;
  int v[8]; int s = 0;
  #pragma unroll
  for (int i=0;i<8;++i){ v[i] = s; s += deg[t*8 + i]; }
  int lane = t & 63, w = t >> 6;
  int si = s;
  for (int o=1;o<64;o<<=1){ int u = __shfl_up(si, o); if (lane >= o) si += u; }
  __shared__ int wsum[16];
  if (lane == 63) wsum[w] = si;
  __syncthreads();
  if (t < 16) {
    int x = wsum[t];
    for (int o=1;o<16;o<<=1){ int u = __shfl_up(x, o); if (t >= o) x += u; }
    wsum[t] = x;
  }
  __syncthreads();
  int wbase = (w == 0) ? 0 : wsum[w-1];
  int base = wbase + (si - s);
  #pragma unroll
  for (int i=0;i<8;++i){ int o2 = base + v[i]; off[t*8+i] = o2; cursor[t*8+i] = o2; }
  if (t == 1023) off[8192] = wbase + si;
}

__global__ void k_fill(const int* __restrict__ ei, int* __restrict__ cursor,
                       int* __restrict__ elist){
  int e = blockIdx.x*256 + threadIdx.x; if (e >= 131072) return;
  int d = ei[131072 + e];
  int slot = atomicAdd(&cursor[d], 1);
  elist[slot] = e;
}

// ---------------- GEMM: C/outputs = A[M,K]@Bt[N,K]^T + bias ----------------
// mode 0: A f32 -> C f32.  mode 1: QKV pack epilogue (K and V fragment-order).
// mode 2: A = combine of 4 bf16 O-partials -> C f32.
// mode 3: WGAT epilogue: col<512 -> tb bf16; 512..519 -> scb f32; 520..ncols -> aux f32.
__global__ __launch_bounds__(256) void k_gemm(
    const float* __restrict__ A, int lda,
    const unsigned short* __restrict__ Bt, int K,
    const float* __restrict__ bias,
    float* __restrict__ C, int ldc, int mode,
    const float* __restrict__ xv, const float* __restrict__ wsum,
    unsigned short* __restrict__ qO, unsigned short* __restrict__ kO,
    unsigned short* __restrict__ vO,
    const unsigned short* __restrict__ opA, const float* __restrict__ cw,
    float* __restrict__ aux, int ncols)
{
  __shared__ unsigned short As[128*40];
  __shared__ unsigned short Bs[128*40];
  const int t = threadIdx.x;
  const int wid = t >> 6, l = t & 63;
  const int lr = l & 15, lg = l >> 4;
  const int arow0 = blockIdx.y*128, bn0 = blockIdx.x*128;
  const int wr = (wid >> 1)*64, wc = (wid & 1)*64;
  f4 zero = {0.f,0.f,0.f,0.f};
  f4 acc[4][4];
  #pragma unroll
  for (int i=0;i<4;++i)
    #pragma unroll
    for (int j=0;j<4;++j) acc[i][j] = zero;

  for (int k0 = 0; k0 < K; k0 += 32) {
    #pragma unroll
    for (int p=0;p<4;++p) {
      int row = p*32 + (t>>3);
      int c4  = (t&7)*4;
      ushort4 h4;
      if (mode == 2) {
        const float* w4 = &cw[(arow0+row)*4];
        float a0=0.f,a1=0.f,a2=0.f,a3=0.f;
        #pragma unroll
        for (int s=0;s<4;++s) {
          ushort4 u = *reinterpret_cast<const ushort4*>(
              opA + (size_t)s*3145728 + (size_t)(arow0+row)*384 + k0 + c4);
          float wv = w4[s];
          a0 += b2f(u.x)*wv; a1 += b2f(u.y)*wv; a2 += b2f(u.z)*wv; a3 += b2f(u.w)*wv;
        }
        h4.x = f2b(a0); h4.y = f2b(a1); h4.z = f2b(a2); h4.w = f2b(a3);
      } else {
        float4 v = *reinterpret_cast<const float4*>(A + (size_t)(arow0+row)*lda + k0 + c4);
        h4.x = f2b(v.x); h4.y = f2b(v.y); h4.z = f2b(v.z); h4.w = f2b(v.w);
      }
      *reinterpret_cast<ushort4*>(&As[row*40 + c4]) = h4;
    }
    #pragma unroll
    for (int p=0;p<2;++p) {
      int n  = p*64 + (t>>2);
      int c8 = (t&3)*8;
      int4 v = *reinterpret_cast<const int4*>(Bt + (size_t)(bn0+n)*K + k0 + c8);
      *reinterpret_cast<int4*>(&Bs[n*40 + c8]) = v;
    }
    __syncthreads();
    bfrag af[4], bfm[4];
    #pragma unroll
    for (int mi=0;mi<4;++mi) af[mi] = *reinterpret_cast<const bfrag*>(&As[(wr+mi*16+lr)*40 + lg*8]);
    #pragma unroll
    for (int ni=0;ni<4;++ni) bfm[ni] = *reinterpret_cast<const bfrag*>(&Bs[(wc+ni*16+lr)*40 + lg*8]);
    #pragma unroll
    for (int mi=0;mi<4;++mi)
      #pragma unroll
      for (int ni=0;ni<4;++ni)
        acc[mi][ni] = MFMA(af[mi], bfm[ni], acc[mi][ni]);
    __syncthreads();
  }
  #pragma unroll
  for (int mi=0;mi<4;++mi) {
    #pragma unroll
    for (int ni=0;ni<4;++ni) {
      int col = bn0 + wc + ni*16 + lr;
      float bv = bias[col];
      float wsv = (mode==1) ? wsum[col] : 0.f;
      #pragma unroll
      for (int i=0;i<4;++i) {
        int row = arow0 + wr + mi*16 + lg*4 + i;
        float val = acc[mi][ni][i] + bv;
        if (mode == 1) {
          val += xv[row]*wsv;
          if (col < 384) val *= 0.05103103631f;   // fold attention scale into Q
          unsigned short hv = f2b(val);
          if (col < 384)      qO[(size_t)row*384 + col] = hv;
          else if (col < 768) {
            // K in MFMA A-frag order: K'[j>>5][(j>>4)&1][c>>5][j&15][(c>>3)&3][c&7]
            int c = col - 384, j = row;
            size_t kidx = (size_t)(j >> 5)*12288 + (size_t)((j >> 4) & 1)*6144
                        + (size_t)(c >> 5)*512 + (size_t)(j & 15)*32
                        + (size_t)((c >> 3) & 3)*8 + (c & 7);
            kO[kidx] = hv;
          } else {
            // V in MFMA B-frag order: V'[j>>5][d>>4][d&15][(j&31)>>3][j&7]
            int d = col - 768, j = row;
            size_t vidx = (size_t)(j >> 5)*12288 + (size_t)(d >> 4)*512
                        + (size_t)(d & 15)*32 + (size_t)((j & 31) >> 3)*8 + (j & 7);
            vO[vidx] = hv;
          }
        } else if (mode == 3) {
          if (col < 512)      qO[(size_t)row*512 + col] = f2b(val);
          else if (col < 520) C[(size_t)row*8 + col - 512] = val;
          else if (col < ncols) aux[(size_t)row*128 + col - 520] = val;
        } else {
          C[(size_t)row*ldc + col] = val;
        }
      }
    }
  }
}

// ---------------- flash attention v8: K AND V warp-private from global (fragment
//   order, L1-broadcast across warps), no staging, Ps double-buffered, ONE barrier/iter ----------------
__global__ __launch_bounds__(256,2) void k_flash(
    const unsigned short* __restrict__ qg,
    const unsigned short* __restrict__ kg,
    const unsigned short* __restrict__ vg,
    unsigned short* __restrict__ Opart, float* __restrict__ mpart, float* __restrict__ lpart)
{
  __shared__ unsigned short Ps[2][64*40];    // P tile [q][k] bf16, double-buffered
  __shared__ float f_s[2][64];

  const int t = threadIdx.x;
  const int w = t >> 6, l = t & 63;
  const int lr = l & 15, lg = l >> 4;
  const int qbi = blockIdx.x >> 2, split = blockIdx.x & 3;
  const int qbase = qbi * 64;

  bfrag qf[12];
  #pragma unroll
  for (int kk=0;kk<12;++kk)
    qf[kk] = *reinterpret_cast<const bfrag*>(qg + (size_t)(qbase + w*16 + lr)*384 + kk*32 + lg*8);

  f4 zero = {0.f,0.f,0.f,0.f};
  f4 o[4][6];
  #pragma unroll
  for (int a=0;a<4;++a)
    #pragma unroll
    for (int b=0;b<6;++b) o[a][b] = zero;

  float m = -3e38f, lsum = 0.f;
  const int j0beg = split*2048, jend = j0beg + 2048;

  for (int j0 = j0beg; j0 < jend; j0 += 32) {
    const int jt = j0 >> 5;
    const int buf = jt & 1;

    // ---- QK^T (swapped): A = K fragments straight from global (identical across
    //      warps -> L1 broadcast), B = Q regs -> S[key][q=lr]
    const unsigned short* kbase = kg + (size_t)jt*12288 + lr*32 + lg*8;
    f4 s0 = zero, s1 = zero;
    __builtin_amdgcn_s_setprio(1);
    #pragma unroll
    for (int kk=0;kk<12;++kk) {
      bfrag k0 = *reinterpret_cast<const bfrag*>(kbase + kk*512);
      bfrag k1 = *reinterpret_cast<const bfrag*>(kbase + 6144 + kk*512);
      s0 = MFMA(k0, qf[kk], s0);
      s1 = MFMA(k1, qf[kk], s1);
      if ((kk & 3) == 3) __builtin_amdgcn_sched_barrier(0);   // cap load hoisting
    }
    __builtin_amdgcn_s_setprio(0);

    // ---- lane-local online softmax with defer-max (THR=8)
    float mt = fmaxf(fmaxf(fmaxf(s0[0],s0[1]),fmaxf(s0[2],s0[3])),
                     fmaxf(fmaxf(s1[0],s1[1]),fmaxf(s1[2],s1[3])));
    mt = fmaxf(mt, __shfl_xor(mt,16));
    mt = fmaxf(mt, __shfl_xor(mt,32));
    bool grew = mt > m + 8.f;
    bool doresc = __any(grew);
    float mn = doresc ? fmaxf(m, mt) : m;
    float p0[4], p1[4];
    float sum = 0.f;
    #pragma unroll
    for (int i=0;i<4;++i) {
      p0[i] = __expf(s0[i]-mn); p1[i] = __expf(s1[i]-mn);
      sum += p0[i] + p1[i];
    }
    sum += __shfl_xor(sum,16);
    sum += __shfl_xor(sum,32);
    float f = 1.f;
    if (doresc) {
      f = __expf(m - mn);
      lsum = lsum * f + sum;
      m = mn;
    } else {
      lsum += sum;
    }

    // ---- write P tile + f into buffer `buf`
    unsigned int pk0 = (unsigned int)f2b(p0[0]) | ((unsigned int)f2b(p0[1]) << 16);
    unsigned int pk1 = (unsigned int)f2b(p0[2]) | ((unsigned int)f2b(p0[3]) << 16);
    unsigned int pk2 = (unsigned int)f2b(p1[0]) | ((unsigned int)f2b(p1[1]) << 16);
    unsigned int pk3 = (unsigned int)f2b(p1[2]) | ((unsigned int)f2b(p1[3]) << 16);
    int prow = (w*16 + lr)*40;
    *reinterpret_cast<unsigned int*>(&Ps[buf][prow + lg*4])          = pk0;
    *reinterpret_cast<unsigned int*>(&Ps[buf][prow + lg*4 + 2])      = pk1;
    *reinterpret_cast<unsigned int*>(&Ps[buf][prow + 16 + lg*4])     = pk2;
    *reinterpret_cast<unsigned int*>(&Ps[buf][prow + 16 + lg*4 + 2]) = pk3;
    if (lg == 0) f_s[buf][w*16 + lr] = f;

    __syncthreads();   // single barrier: Ps[buf]/f_s[buf] ready (prev buf's PV done >=1 barrier ago)

    // ---- V fragments direct from global (fragment-order, warp-private d-slice)
    bfrag vf[6];
    #pragma unroll
    for (int dt=0;dt<6;++dt)
      vf[dt] = *reinterpret_cast<const bfrag*>(
          vg + (size_t)jt*12288 + (size_t)(w*6 + dt)*512 + lr*32 + lg*8);

    // ---- PV: warp owns d-cols w*96..w*96+95, all 64 q-rows
    bfrag pf[4];
    #pragma unroll
    for (int qt=0;qt<4;++qt)
      pf[qt] = *reinterpret_cast<const bfrag*>(&Ps[buf][(qt*16+lr)*40 + lg*8]);
    #pragma unroll
    for (int qt=0;qt<4;++qt) {
      #pragma unroll
      for (int i=0;i<4;++i) {
        float frv = f_s[buf][qt*16 + lg*4 + i];
        #pragma unroll
        for (int dt=0;dt<6;++dt) o[qt][dt][i] *= frv;
      }
    }
    __builtin_amdgcn_s_setprio(1);
    #pragma unroll
    for (int qt=0;qt<4;++qt)
      #pragma unroll
      for (int dt=0;dt<6;++dt)
        o[qt][dt] = MFMA(pf[qt], vf[dt], o[qt][dt]);
    __builtin_amdgcn_s_setprio(0);
    __builtin_amdgcn_sched_barrier(0);
  }

  unsigned short* Op = Opart + (size_t)split*8192*384;
  #pragma unroll
  for (int qt=0;qt<4;++qt)
    #pragma unroll
    for (int dt=0;dt<6;++dt)
      #pragma unroll
      for (int i=0;i<4;++i)
        Op[(size_t)(qbase + qt*16 + lg*4 + i)*384 + w*96 + dt*16 + lr] = f2b(o[qt][dt][i]);
  if (lg == 0) {
    mpart[split*8192 + qbase + w*16 + lr] = m;
    lpart[split*8192 + qbase + w*16 + lr] = lsum;
  }
}

// per-row combine weights: cw[row][s] = exp(m_s - M) / L  (4 splits)
__global__ void k_cw(const float* __restrict__ mp, const float* __restrict__ lp,
                     float* __restrict__ cw)
{
  int r = blockIdx.x*256 + threadIdx.x;   // 8192
  float m0 = mp[r], m1 = mp[8192+r], m2 = mp[16384+r], m3 = mp[24576+r];
  float M = fmaxf(fmaxf(m0,m1), fmaxf(m2,m3));
  float w0 = __expf(m0-M), w1 = __expf(m1-M), w2 = __expf(m2-M), w3 = __expf(m3-M);
  float L = lp[r]*w0 + lp[8192+r]*w1 + lp[16384+r]*w2 + lp[24576+r]*w3;
  float inv = 1.f / L;
  float4 o4 = make_float4(w0*inv, w1*inv, w2*inv, w3*inv);
  *reinterpret_cast<float4*>(&cw[r*4]) = o4;
}

// ---------------- LN1 + SiLU + residual ----------------
__global__ __launch_bounds__(256) void k_ln1(const float* __restrict__ pre, const float* __restrict__ Ei,
                      const float* __restrict__ g, const float* __restrict__ b,
                      float* __restrict__ out)
{
  int row = blockIdx.x, c = threadIdx.x;
  float v = pre[(size_t)row*256 + c];
  float s1 = v, s2 = v*v;
  #pragma unroll
  for (int o1=32;o1;o1>>=1){ s1 += __shfl_down(s1,o1); s2 += __shfl_down(s2,o1); }
  __shared__ float a1[4], a2[4];
  if ((c&63)==0){ a1[c>>6] = s1; a2[c>>6] = s2; }
  __syncthreads();
  float S1 = a1[0]+a1[1]+a1[2]+a1[3], S2 = a2[0]+a2[1]+a2[2]+a2[3];
  float mean = S1*(1.f/256.f), var = S2*(1.f/256.f) - mean*mean;
  float y = (v-mean)*rsqrtf(var+1e-5f)*g[c] + b[c];
  float sig = 1.f/(1.f+__expf(-y));
  out[(size_t)row*256 + c] = y*sig + Ei[(size_t)row*256 + c];
}

// ---------------- edge kernels ----------------
// scores + per-block (256-edge) online max/sum partials per head
__global__ __launch_bounds__(256) void k_escore(const int* __restrict__ ei, const float* __restrict__ ea,
                         const float* __restrict__ SC, float* __restrict__ sc,
                         float* __restrict__ pm, float* __restrict__ ps)
{
  int e = blockIdx.x*256 + threadIdx.x;
  int s = ei[e], d = ei[131072 + e];
  float wv = ea[e];
  float4 ai = *reinterpret_cast<const float4*>(&SC[(size_t)d*8]);      // wi scores (x_i = dst)
  float4 aj = *reinterpret_cast<const float4*>(&SC[(size_t)s*8 + 4]);  // wj scores (x_j = src)
  float4 o4 = make_float4((ai.x+aj.x)*wv, (ai.y+aj.y)*wv, (ai.z+aj.z)*wv, (ai.w+aj.w)*wv);
  *reinterpret_cast<float4*>(&sc[e*4]) = o4;

  float sv[4] = {o4.x, o4.y, o4.z, o4.w};
  __shared__ float sm_[4][4], ss_[4][4];
  int lane = threadIdx.x & 63, wvid = threadIdx.x >> 6;
  #pragma unroll
  for (int h=0; h<4; ++h) {
    float m = sv[h], s2 = 1.f;
    #pragma unroll
    for (int o1=32;o1;o1>>=1) {
      float om = __shfl_xor(m,o1), os = __shfl_xor(s2,o1);
      float M2 = fmaxf(m,om);
      s2 = s2*__expf(m-M2) + os*__expf(om-M2);
      m = M2;
    }
    if (lane==0){ sm_[wvid][h]=m; ss_[wvid][h]=s2; }
  }
  __syncthreads();
  if (threadIdx.x < 4) {
    int h = threadIdx.x;
    float M = sm_[0][h], S = ss_[0][h];
    #pragma unroll
    for (int i=1;i<4;++i){
      float M2 = fmaxf(M, sm_[i][h]);
      S = S*__expf(M-M2) + ss_[i][h]*__expf(sm_[i][h]-M2);
      M = M2;
    }
    pm[blockIdx.x*4+h] = M; ps[blockIdx.x*4+h] = S;
  }
}

// combine 128 block-partials per (chunk, head)
__global__ __launch_bounds__(128) void k_cfin(const float* __restrict__ pm, const float* __restrict__ ps,
                                              float* __restrict__ mx, float* __restrict__ sm)
{
  int ch = blockIdx.x;          // c*4+h, 16 total
  int c = ch >> 2, h = ch & 3;
  int t = threadIdx.x;          // 128 partial blocks per chunk
  float M = pm[(c*128 + t)*4 + h], S = ps[(c*128 + t)*4 + h];
  int lane = t & 63;
  #pragma unroll
  for (int o1=32;o1;o1>>=1){
    float om = __shfl_xor(M,o1), os = __shfl_xor(S,o1);
    float M2 = fmaxf(M,om);
    S = S*__expf(M-M2) + os*__expf(om-M2);
    M = M2;
  }
  __shared__ float am[2], as[2];
  if (lane==0){ am[t>>6]=M; as[t>>6]=S; }
  __syncthreads();
  if (t==0){
    float M2 = fmaxf(am[0],am[1]);
    float Sf = as[0]*__expf(am[0]-M2) + as[1]*__expf(am[1]-M2);
    mx[ch]=M2; sm[ch]=Sf;
  }
}

// CSR gather-aggregate over bf16 transform rows; softmax applied inline (pnorm folded)
__global__ __launch_bounds__(128) void k_aggr(const int* __restrict__ off,
                      const int* __restrict__ elist, const int* __restrict__ ei,
                      const float* __restrict__ sc,
                      const float* __restrict__ mx, const float* __restrict__ sm,
                      const unsigned short* __restrict__ Tb, float* __restrict__ g)
{
  int n = blockIdx.x, d = threadIdx.x;
  int qb = off[n], qe = off[n+1];
  float acc = 0.f;
  for (int q = qb; q < qe; ++q) {
    int e = elist[q];
    int s = ei[e];
    int ch = (e >> 15) * 4;
    float4 sv = *reinterpret_cast<const float4*>(&sc[e*4]);
    float px = __expf(sv.x - mx[ch+0]) / sm[ch+0];
    float py = __expf(sv.y - mx[ch+1]) / sm[ch+1];
    float pz = __expf(sv.z - mx[ch+2]) / sm[ch+2];
    float pw = __expf(sv.w - mx[ch+3]) / sm[ch+3];
    const unsigned short* Tr = Tb + (size_t)s*512;
    acc += px*b2f(Tr[d]) + py*b2f(Tr[128+d]) + pz*b2f(Tr[256+d]) + pw*b2f(Tr[384+d]);
  }
  g[(size_t)n*128 + d] = acc;
}

// ---------------- final: skip1 GEMV + combine + LN2 ----------------
__global__ __launch_bounds__(128) void k_final(const float* __restrict__ g1, const float* __restrict__ aux,
                       const float* __restrict__ sw, const float* __restrict__ sb,
                       const float* __restrict__ lg2, const float* __restrict__ lb2,
                       float* __restrict__ out)
{
  int row = blockIdx.x, c = threadIdx.x;
  __shared__ float gr[128];
  float gv = g1[(size_t)row*128 + c];
  gr[c] = gv; __syncthreads();
  float s1 = sb[c];
  #pragma unroll 8
  for (int k=0;k<128;++k) s1 += gr[k]*sw[k*128 + c];
  float s0 = aux[(size_t)row*128 + c];
  float v = gv + 0.5f*(s0 + s1);
  float m1 = v, m2 = v*v;
  #pragma unroll
  for (int o1=32;o1;o1>>=1){ m1 += __shfl_down(m1,o1); m2 += __shfl_down(m2,o1); }
  __shared__ float a1[2], a2[2];
  if ((c&63)==0){ a1[c>>6]=m1; a2[c>>6]=m2; }
  __syncthreads();
  float S1 = a1[0]+a1[1], S2 = a2[0]+a2[1];
  float mean = S1*(1.f/128.f), var = S2*(1.f/128.f) - mean*mean;
  out[(size_t)row*128 + c] = (v-mean)*rsqrtf(var+1e-5f)*lg2[c] + lb2[c];
}

// ---------------- host launch ----------------
extern "C" void kernel_launch(void* const* d_in, const int* in_sizes, int n_in,
                              void* d_out, int out_size, void* d_ws, size_t ws_size,
                              hipStream_t stream)
{
  const int*   ids    = (const int*)  d_in[0];
  const float* x      = (const float*)d_in[1];
  const float* ea     = (const float*)d_in[2];
  const int*   eidx   = (const int*)  d_in[3];
  const float* embed  = (const float*)d_in[4];
  const float* qkv_w  = (const float*)d_in[5];
  const float* qkv_b  = (const float*)d_in[6];
  const float* proj_w = (const float*)d_in[7];
  const float* proj_b = (const float*)d_in[8];
  const float* fuse_w = (const float*)d_in[9];
  const float* fuse_b = (const float*)d_in[10];
  const float* ln1_g  = (const float*)d_in[11];
  const float* ln1_b  = (const float*)d_in[12];
  const float* wi0 = (const float*)d_in[13]; const float* bi0 = (const float*)d_in[14];
  const float* wj0 = (const float*)d_in[15]; const float* bj0 = (const float*)d_in[16];
  const float* wt0 = (const float*)d_in[17]; const float* bt0 = (const float*)d_in[18];
  const float* attn0 = (const float*)d_in[19];
  const float* sk0w = (const float*)d_in[20]; const float* sk0b = (const float*)d_in[21];
  const float* wi1 = (const float*)d_in[22]; const float* bi1 = (const float*)d_in[23];
  const float* wj1 = (const float*)d_in[24]; const float* bj1 = (const float*)d_in[25];
  const float* wt1 = (const float*)d_in[26]; const float* bt1 = (const float*)d_in[27];
  const float* attn1 = (const float*)d_in[28];
  const float* sk1w = (const float*)d_in[29]; const float* sk1b = (const float*)d_in[30];
  const float* ln2_g = (const float*)d_in[31]; const float* ln2_b = (const float*)d_in[32];

  char* ws = (char*)d_ws;
  const size_t MBy = (size_t)1 << 20;

  // static area (0..2MB), zeroed each call
  unsigned short* BtQKV  = (unsigned short*)(ws + 0);
  unsigned short* BtW2   = (unsigned short*)(ws + 589824);   // 196608 B
  float* biasW2 = (float*)(ws + 884736);                     // 1024 B
  unsigned short* BtT0   = (unsigned short*)(ws + 1081344);  // 640x256x2
  unsigned short* BtT1   = (unsigned short*)(ws + 1409024);  // 768x128x2
  float* biasT0 = (float*)(ws + 1605632);
  float* biasT1 = (float*)(ws + 1608192);
  float* wsum   = (float*)(ws + 1611264);
  float* mxb    = (float*)(ws + 1615872);
  float* smb    = (float*)(ws + 1615936);
  int* deg    = (int*)(ws + 1703936);
  int* cursor = (int*)(ws + 1736704);
  int* off    = (int*)(ws + 1769472);
  float* cw   = (float*)(ws + 1806336);                      // 131072 B -> ends 1937408
  float* pm   = (float*)(ws + 1937408);                      // 8192 B
  float* ps   = (float*)(ws + 1945600);                      // 8192 B

  float* Ei   = (float*)(ws + 2*MBy);                   // 2..10
  unsigned short* qb = (unsigned short*)(ws + 10*MBy);  // 10..16.3
  unsigned short* kb = (unsigned short*)(ws + 17*MBy);  // 17..23.3 (fragment-order)
  unsigned short* vb = (unsigned short*)(ws + 24*MBy);  // 24..30.3 (fragment-order)
  unsigned short* Opart = (unsigned short*)(ws + 31*MBy);  // 31..55 (4 x 6MB bf16 partials)
  float* mpart = (float*)(ws + 55*MBy);                 // 128KB
  float* lpart = (float*)(ws + 55*MBy + 131072);        // 128KB -> ends 55.25MB
  float* pre  = (float*)(ws + 10*MBy);                  // over qb (dead after flash)
  float* emb0 = (float*)(ws + 31*MBy);                  // over Opart head (dead after mode-2)
  unsigned short* TCb0 = (unsigned short*)(ws + 39*MBy);// 39..47 (bf16 8192x512)
  float* SCb0 = (float*)(ws + 47*MBy);                  // 256KB
  float* SCb1 = (float*)(ws + 47*MBy + 262144);         // 256KB -> 47.5
  float* AUX  = (float*)(ws + 47*MBy + 524288);         // 47.5..51.5 (f32 8192x128)
  float* sc0  = (float*)(ws + 52*MBy);                  // 52..54
  float* sc1  = (float*)(ws + 54*MBy);                  // 54..56 (mpart/lpart dead by then)
  unsigned short* TCb1 = (unsigned short*)(ws + 18*MBy);// 18..26 (kb/vb dead)
  float* g0   = (float*)(ws + 2*MBy);                   // over Ei (dead after ln1)
  float* g1   = (float*)(ws + 6*MBy);                   // over Ei tail
  int* elist  = (int*)(ws + 62*MBy);                    // 62..62.5

  float* out = (float*)d_out;

  hipMemsetAsync(ws, 0, 2*MBy, stream);

  // prep: weight transforms + Ei gather + output copy (embed + ids)
  k_prep<<<16939, 256, 0, stream>>>(qkv_w, proj_w, proj_b, fuse_w, fuse_b,
                                    wt0, wt1, sk0w,
                                    wi0, bi0, wj0, bj0, wi1, bi1, wj1, bj1,
                                    attn0, attn1, bt0, bt1, sk0b, embed, ids,
                                    BtQKV, BtW2, BtT0, BtT1,
                                    biasW2, biasT0, biasT1, wsum, Ei, out);
  k_deg<<<512, 256, 0, stream>>>(eidx, deg);
  k_scan<<<1, 1024, 0, stream>>>(deg, off, cursor);
  k_fill<<<512, 256, 0, stream>>>(eidx, cursor, elist);

  // QKV GEMM with rank-1 x term, packing q(scaled) + K/V fragment-order bf16
  k_gemm<<<dim3(9,64), 256, 0, stream>>>(Ei, 256, BtQKV, 256, qkv_b, nullptr, 0, 1,
                                         x, wsum, qb, kb, vb, nullptr, nullptr,
                                         nullptr, 0);
  k_flash<<<512, 256, 0, stream>>>(qb, kb, vb, Opart, mpart, lpart);
  k_cw<<<32, 256, 0, stream>>>(mpart, lpart, cw);

  // fused (combine -> att) @ (proj_w@fuse_w) + bias2  ->  pre
  k_gemm<<<dim3(2,64), 256, 0, stream>>>(nullptr, 0, BtW2, 384, biasW2, pre, 256, 2,
                                         nullptr, nullptr, nullptr, nullptr, nullptr,
                                         Opart, cw, nullptr, 0);
  k_ln1<<<8192, 256, 0, stream>>>(pre, Ei, ln1_g, ln1_b, emb0);

  // WGAT layer 0: transform -> bf16 TCb0, scores -> SCb0
  k_gemm<<<dim3(5,64), 256, 0, stream>>>(emb0, 256, BtT0, 256, biasT0, SCb0, 0, 3,
                                         nullptr, nullptr, TCb0, nullptr, nullptr,
                                         nullptr, nullptr, AUX, 520);
  k_escore<<<512, 256, 0, stream>>>(eidx, ea, SCb0, sc0, pm, ps);
  k_cfin<<<16, 128, 0, stream>>>(pm, ps, mxb, smb);
  k_aggr<<<8192, 128, 0, stream>>>(off, elist, eidx, sc0, mxb, smb, TCb0, g0);

  // WGAT layer 1: transform -> bf16 TCb1, scores -> SCb1, skip0 -> AUX
  k_gemm<<<dim3(6,64), 256, 0, stream>>>(g0, 128, BtT1, 128, biasT1, SCb1, 0, 3,
                                         nullptr, nullptr, TCb1, nullptr, nullptr,
                                         nullptr, nullptr, AUX, 648);
  k_escore<<<512, 256, 0, stream>>>(eidx, ea, SCb1, sc1, pm, ps);
  k_cfin<<<16, 128, 0, stream>>>(pm, ps, mxb, smb);
  k_aggr<<<8192, 128, 0, stream>>>(off, elist, eidx, sc1, mxb, smb, TCb1, g1);

  k_final<<<8192, 128, 0, stream>>>(g1, AUX, sk1w, sk1b, ln2_g, ln2_b, out);
}

// Round 13
// 445.627 us; speedup vs baseline: 1.3963x; 1.3963x over previous
//
#include <hip/hip_runtime.h>

typedef __attribute__((ext_vector_type(8))) short bfrag;   // 8 x bf16
typedef __attribute__((ext_vector_type(4))) float f4;

#define MFMA(a,b,c) __builtin_amdgcn_mfma_f32_16x16x32_bf16(a,b,c,0,0,0)

__device__ __forceinline__ unsigned short f2b(float x){
  union { float f; unsigned int u; } v; v.f = x;
  unsigned int r = v.u + 0x7fffu + ((v.u >> 16) & 1u);
  return (unsigned short)(r >> 16);
}
__device__ __forceinline__ float b2f(unsigned short h){
  union { unsigned int u; float f; } v; v.u = ((unsigned int)h) << 16;
  return v.f;
}

// ---------------- merged prep kernel (weights + gathers + output copy) ----------------
__global__ __launch_bounds__(256) void k_prep(
    const float* __restrict__ qkv_w, const float* __restrict__ proj_w,
    const float* __restrict__ proj_b, const float* __restrict__ fuse_w,
    const float* __restrict__ fuse_b,
    const float* __restrict__ wt0,
    const float* __restrict__ wt1, const float* __restrict__ sk0w,
    const float* __restrict__ wi0, const float* __restrict__ bi0,
    const float* __restrict__ wj0, const float* __restrict__ bj0,
    const float* __restrict__ wi1, const float* __restrict__ bi1,
    const float* __restrict__ wj1, const float* __restrict__ bj1,
    const float* __restrict__ attn0, const float* __restrict__ attn1,
    const float* __restrict__ bt0, const float* __restrict__ bt1,
    const float* __restrict__ sk0b,
    const float* __restrict__ embed, const int* __restrict__ ids,
    unsigned short* __restrict__ BtQKV, unsigned short* __restrict__ BtW2,
    unsigned short* __restrict__ BtT0, unsigned short* __restrict__ BtT1,
    float* __restrict__ biasW2,
    float* __restrict__ biasT0, float* __restrict__ biasT1,
    float* __restrict__ wsum, float* __restrict__ Ei,
    float* __restrict__ out)
{
  int b = blockIdx.x, t = threadIdx.x;
  if (b < 1152) {            // QKV weight rows 128..383, transpose to [1152][256]
    int idx = b*256 + t; int k = idx/1152, n = idx - k*1152;
    BtQKV[(size_t)n*256 + k] = f2b(qkv_w[128*1152 + idx]);
  } else if (b < 1536) {     // W2 = proj_w @ fuse_w  -> Bt layout [256][384]
    int k = b - 1152;        // 0..383
    float s = 0.f;
    for (int j = 0; j < 384; ++j) s += proj_w[(size_t)k*384 + j] * fuse_w[(size_t)j*256 + t];
    BtW2[(size_t)t*384 + k] = f2b(s);
  } else if (b == 1536) {    // bias2 = proj_b @ fuse_w + fuse_b
    float s = fuse_b[t];
    for (int j = 0; j < 384; ++j) s += proj_b[j] * fuse_w[(size_t)j*256 + t];
    biasW2[t] = s;
  } else if (b < 2049) {     // wt0 256x512
    int idx = (b-1537)*256 + t; int k = idx/512, n = idx - k*512;
    BtT0[(size_t)n*256 + k] = f2b(wt0[idx]);
  } else if (b < 2305) {     // wt1 128x512
    int idx = (b-2049)*256 + t; int k = idx/512, n = idx - k*512;
    BtT1[(size_t)n*128 + k] = f2b(wt1[idx]);
  } else if (b < 2369) {     // sk0w 128x128 -> rows 520..647 of BtT1
    int idx = (b-2305)*256 + t; int k = idx/128, n = idx - k*128;
    BtT1[(size_t)(520+n)*128 + k] = f2b(sk0w[idx]);
  } else if (b < 2373) {     // attnred wi0 (K=256) -> BtT0 rows 512..515
    int idx = (b-2369)*256 + t;
    int h = idx >> 8, k = idx & 255;
    float s = 0.f;
    for (int d = 0; d < 128; ++d) s += wi0[(size_t)k*512 + h*128 + d] * attn0[h*128 + d];
    BtT0[(size_t)(512 + h)*256 + k] = f2b(s);
    if (idx < 4) {
      float sb = 0.f;
      for (int d = 0; d < 128; ++d) sb += bi0[idx*128 + d] * attn0[idx*128 + d];
      biasT0[512 + idx] = sb;
    }
  } else if (b < 2377) {     // attnred wj0 -> BtT0 rows 516..519
    int idx = (b-2373)*256 + t;
    int h = idx >> 8, k = idx & 255;
    float s = 0.f;
    for (int d = 0; d < 128; ++d) s += wj0[(size_t)k*512 + h*128 + d] * attn0[h*128 + d];
    BtT0[(size_t)(516 + h)*256 + k] = f2b(s);
    if (idx < 4) {
      float sb = 0.f;
      for (int d = 0; d < 128; ++d) sb += bj0[idx*128 + d] * attn0[idx*128 + d];
      biasT0[516 + idx] = sb;
    }
  } else if (b < 2379) {     // attnred wi1 (K=128) -> BtT1 rows 512..515
    int idx = (b-2377)*256 + t;
    int h = idx >> 7, k = idx & 127;
    float s = 0.f;
    for (int d = 0; d < 128; ++d) s += wi1[(size_t)k*512 + h*128 + d] * attn1[h*128 + d];
    BtT1[(size_t)(512 + h)*128 + k] = f2b(s);
    if (idx < 4) {
      float sb = 0.f;
      for (int d = 0; d < 128; ++d) sb += bi1[idx*128 + d] * attn1[idx*128 + d];
      biasT1[512 + idx] = sb;
    }
  } else if (b < 2381) {     // attnred wj1 -> BtT1 rows 516..519
    int idx = (b-2379)*256 + t;
    int h = idx >> 7, k = idx & 127;
    float s = 0.f;
    for (int d = 0; d < 128; ++d) s += wj1[(size_t)k*512 + h*128 + d] * attn1[h*128 + d];
    BtT1[(size_t)(516 + h)*128 + k] = f2b(s);
    if (idx < 4) {
      float sb = 0.f;
      for (int d = 0; d < 128; ++d) sb += bj1[idx*128 + d] * attn1[idx*128 + d];
      biasT1[516 + idx] = sb;
    }
  } else if (b < 2383) {     // copy bt0 -> biasT0[0..511]
    int idx = (b-2381)*256 + t; biasT0[idx] = bt0[idx];
  } else if (b < 2385) {     // copy bt1 -> biasT1[0..511]
    int idx = (b-2383)*256 + t; biasT1[idx] = bt1[idx];
  } else if (b == 2385) {    // copy sk0b -> biasT1[520..647]
    if (t < 128) biasT1[520 + t] = sk0b[t];
  } else if (b < 2391) {     // wsum
    int n = (b-2386)*256 + t;
    if (n < 1152) {
      float s = 0.f;
      for (int k = 0; k < 128; ++k) s += qkv_w[(size_t)k*1152 + n];
      wsum[n] = s;
    }
  } else if (b < 4439) {     // gather Ei (float4): 524288 elems
    int idx = (b-2391)*256 + t;
    int n = idx >> 6, c4 = idx & 63;
    reinterpret_cast<float4*>(Ei)[idx] =
        reinterpret_cast<const float4*>(embed + (size_t)ids[n]*256)[c4];
  } else {                   // output copy: embed -> out[1048576..], ids -> tail
    int i = (b-4439)*256 + t;
    if (i < 3200000)
      reinterpret_cast<float4*>(out)[262144 + i] = reinterpret_cast<const float4*>(embed)[i];
    if (i < 8192) out[13848576 + i] = (float)ids[i];
  }
}

// ---------------- CSR build ----------------
__global__ void k_deg(const int* __restrict__ ei, int* __restrict__ deg){
  int e = blockIdx.x*256 + threadIdx.x; if (e >= 131072) return;
  atomicAdd(&deg[ei[131072 + e]], 1);
}

__global__ __launch_bounds__(1024) void k_scan(const int* __restrict__ deg,
                                               int* __restrict__ off, int* __restrict__ cursor){
  int t = threadIdx.x;
  int v[8]; int s = 0;
  #pragma unroll
  for (int i=0;i<8;++i){ v[i] = s; s += deg[t*8 + i]; }
  int lane = t & 63, w = t >> 6;
  int si = s;
  for (int o=1;o<64;o<<=1){ int u = __shfl_up(si, o); if (lane >= o) si += u; }
  __shared__ int wsum[16];
  if (lane == 63) wsum[w] = si;
  __syncthreads();
  if (t < 16) {
    int x = wsum[t];
    for (int o=1;o<16;o<<=1){ int u = __shfl_up(x, o); if (t >= o) x += u; }
    wsum[t] = x;
  }
  __syncthreads();
  int wbase = (w == 0) ? 0 : wsum[w-1];
  int base = wbase + (si - s);
  #pragma unroll
  for (int i=0;i<8;++i){ int o2 = base + v[i]; off[t*8+i] = o2; cursor[t*8+i] = o2; }
  if (t == 1023) off[8192] = wbase + si;
}

__global__ void k_fill(const int* __restrict__ ei, int* __restrict__ cursor,
                       int* __restrict__ elist){
  int e = blockIdx.x*256 + threadIdx.x; if (e >= 131072) return;
  int d = ei[131072 + e];
  int slot = atomicAdd(&cursor[d], 1);
  elist[slot] = e;
}

// ---------------- GEMM: C/outputs = A[M,K]@Bt[N,K]^T + bias ----------------
// mode 0: A f32 -> C f32.  mode 1: QKV pack epilogue (K row-major, V fragment-order).
// mode 2: A = combine of 4 bf16 O-partials -> C f32.
// mode 3: WGAT epilogue: col<512 -> tb bf16; 512..519 -> scb f32; 520..ncols -> aux f32.
__global__ __launch_bounds__(256) void k_gemm(
    const float* __restrict__ A, int lda,
    const unsigned short* __restrict__ Bt, int K,
    const float* __restrict__ bias,
    float* __restrict__ C, int ldc, int mode,
    const float* __restrict__ xv, const float* __restrict__ wsum,
    unsigned short* __restrict__ qO, unsigned short* __restrict__ kO,
    unsigned short* __restrict__ vO,
    const unsigned short* __restrict__ opA, const float* __restrict__ cw,
    float* __restrict__ aux, int ncols)
{
  __shared__ unsigned short As[128*40];
  __shared__ unsigned short Bs[128*40];
  const int t = threadIdx.x;
  const int wid = t >> 6, l = t & 63;
  const int lr = l & 15, lg = l >> 4;
  const int arow0 = blockIdx.y*128, bn0 = blockIdx.x*128;
  const int wr = (wid >> 1)*64, wc = (wid & 1)*64;
  f4 zero = {0.f,0.f,0.f,0.f};
  f4 acc[4][4];
  #pragma unroll
  for (int i=0;i<4;++i)
    #pragma unroll
    for (int j=0;j<4;++j) acc[i][j] = zero;

  for (int k0 = 0; k0 < K; k0 += 32) {
    #pragma unroll
    for (int p=0;p<4;++p) {
      int row = p*32 + (t>>3);
      int c4  = (t&7)*4;
      ushort4 h4;
      if (mode == 2) {
        const float* w4 = &cw[(arow0+row)*4];
        float a0=0.f,a1=0.f,a2=0.f,a3=0.f;
        #pragma unroll
        for (int s=0;s<4;++s) {
          ushort4 u = *reinterpret_cast<const ushort4*>(
              opA + (size_t)s*3145728 + (size_t)(arow0+row)*384 + k0 + c4);
          float wv = w4[s];
          a0 += b2f(u.x)*wv; a1 += b2f(u.y)*wv; a2 += b2f(u.z)*wv; a3 += b2f(u.w)*wv;
        }
        h4.x = f2b(a0); h4.y = f2b(a1); h4.z = f2b(a2); h4.w = f2b(a3);
      } else {
        float4 v = *reinterpret_cast<const float4*>(A + (size_t)(arow0+row)*lda + k0 + c4);
        h4.x = f2b(v.x); h4.y = f2b(v.y); h4.z = f2b(v.z); h4.w = f2b(v.w);
      }
      *reinterpret_cast<ushort4*>(&As[row*40 + c4]) = h4;
    }
    #pragma unroll
    for (int p=0;p<2;++p) {
      int n  = p*64 + (t>>2);
      int c8 = (t&3)*8;
      int4 v = *reinterpret_cast<const int4*>(Bt + (size_t)(bn0+n)*K + k0 + c8);
      *reinterpret_cast<int4*>(&Bs[n*40 + c8]) = v;
    }
    __syncthreads();
    bfrag af[4], bfm[4];
    #pragma unroll
    for (int mi=0;mi<4;++mi) af[mi] = *reinterpret_cast<const bfrag*>(&As[(wr+mi*16+lr)*40 + lg*8]);
    #pragma unroll
    for (int ni=0;ni<4;++ni) bfm[ni] = *reinterpret_cast<const bfrag*>(&Bs[(wc+ni*16+lr)*40 + lg*8]);
    #pragma unroll
    for (int mi=0;mi<4;++mi)
      #pragma unroll
      for (int ni=0;ni<4;++ni)
        acc[mi][ni] = MFMA(af[mi], bfm[ni], acc[mi][ni]);
    __syncthreads();
  }
  #pragma unroll
  for (int mi=0;mi<4;++mi) {
    #pragma unroll
    for (int ni=0;ni<4;++ni) {
      int col = bn0 + wc + ni*16 + lr;
      float bv = bias[col];
      float wsv = (mode==1) ? wsum[col] : 0.f;
      #pragma unroll
      for (int i=0;i<4;++i) {
        int row = arow0 + wr + mi*16 + lg*4 + i;
        float val = acc[mi][ni][i] + bv;
        if (mode == 1) {
          val += xv[row]*wsv;
          if (col < 384) val *= 0.05103103631f;   // fold attention scale into Q
          unsigned short hv = f2b(val);
          if (col < 384)      qO[(size_t)row*384 + col] = hv;
          else if (col < 768) kO[(size_t)row*384 + col - 384] = hv;
          else {
            // V in MFMA B-frag order: V'[j>>5][d>>4][d&15][(j&31)>>3][j&7]
            int d = col - 768, j = row;
            size_t vidx = (size_t)(j >> 5)*12288 + (size_t)(d >> 4)*512
                        + (size_t)(d & 15)*32 + (size_t)((j & 31) >> 3)*8 + (j & 7);
            vO[vidx] = hv;
          }
        } else if (mode == 3) {
          if (col < 512)      qO[(size_t)row*512 + col] = f2b(val);
          else if (col < 520) C[(size_t)row*8 + col - 512] = val;
          else if (col < ncols) aux[(size_t)row*128 + col - 520] = val;
        } else {
          C[(size_t)row*ldc + col] = val;
        }
      }
    }
  }
}

// ---------------- flash attention (round-8 proven best): KSPLIT=4, K staged in LDS
//   via global_load_lds + XOR swizzle, V direct-from-global (fragment order),
//   lane-local softmax + defer-max, 2 barriers/iter ----------------
__global__ __launch_bounds__(256,2) void k_flash(
    const unsigned short* __restrict__ qg,
    const unsigned short* __restrict__ kg,
    const unsigned short* __restrict__ vg,
    unsigned short* __restrict__ Opart, float* __restrict__ mpart, float* __restrict__ lpart)
{
  __shared__ unsigned short Ks[32*384];      // K tile, XOR-swizzled 16B units
  __shared__ unsigned short Ps[64*40];       // P tile [q][k] bf16
  __shared__ float f_s[64];

  const int t = threadIdx.x;
  const int w = t >> 6, l = t & 63;
  const int lr = l & 15, lg = l >> 4;
  const int qbi = blockIdx.x >> 2, split = blockIdx.x & 3;
  const int qbase = qbi * 64;

  #define STAGE_K(JJ) do { \
    _Pragma("unroll") \
    for (int p_=0;p_<6;++p_) { \
      int idx_ = p_*256 + t; \
      int row_ = idx_ / 48, uu_ = idx_ - row_*48; \
      int ug_ = uu_ ^ (row_ & 7); \
      const unsigned short* gp_ = kg + (size_t)((JJ) + row_)*384 + ug_*8; \
      __builtin_amdgcn_global_load_lds((const __attribute__((address_space(1))) void*)gp_, \
          (__attribute__((address_space(3))) void*)&Ks[idx_*8], 16, 0, 0); \
    } } while(0)

  bfrag qf[12];
  #pragma unroll
  for (int kk=0;kk<12;++kk)
    qf[kk] = *reinterpret_cast<const bfrag*>(qg + (size_t)(qbase + w*16 + lr)*384 + kk*32 + lg*8);

  f4 zero = {0.f,0.f,0.f,0.f};
  f4 o[4][6];
  #pragma unroll
  for (int a=0;a<4;++a)
    #pragma unroll
    for (int b=0;b<6;++b) o[a][b] = zero;

  float m = -3e38f, lsum = 0.f;
  const int j0beg = split*2048, jend = j0beg + 2048;

  STAGE_K(j0beg);
  __syncthreads();

  for (int j0 = j0beg; j0 < jend; j0 += 32) {
    // ---- QK^T (swapped): A = K rows from LDS, B = Q regs -> S[key][q=lr]
    f4 s0 = zero, s1 = zero;
    __builtin_amdgcn_s_setprio(1);
    #pragma unroll
    for (int kk=0;kk<12;++kk) {
      int su = ((kk*4 + lg) ^ (lr & 7)) * 8;
      bfrag k0 = *reinterpret_cast<const bfrag*>(&Ks[lr*384 + su]);
      bfrag k1 = *reinterpret_cast<const bfrag*>(&Ks[(16+lr)*384 + su]);
      s0 = MFMA(k0, qf[kk], s0);
      s1 = MFMA(k1, qf[kk], s1);
    }
    __builtin_amdgcn_s_setprio(0);

    // ---- lane-local online softmax with defer-max (THR=8)
    float mt = fmaxf(fmaxf(fmaxf(s0[0],s0[1]),fmaxf(s0[2],s0[3])),
                     fmaxf(fmaxf(s1[0],s1[1]),fmaxf(s1[2],s1[3])));
    mt = fmaxf(mt, __shfl_xor(mt,16));
    mt = fmaxf(mt, __shfl_xor(mt,32));
    bool grew = mt > m + 8.f;
    bool doresc = __any(grew);
    float mn = doresc ? fmaxf(m, mt) : m;
    float p0[4], p1[4];
    float sum = 0.f;
    #pragma unroll
    for (int i=0;i<4;++i) {
      p0[i] = __expf(s0[i]-mn); p1[i] = __expf(s1[i]-mn);
      sum += p0[i] + p1[i];
    }
    sum += __shfl_xor(sum,16);
    sum += __shfl_xor(sum,32);
    float f = 1.f;
    if (doresc) {
      f = __expf(m - mn);
      lsum = lsum * f + sum;
      m = mn;
    } else {
      lsum += sum;
    }

    // ---- write P tile + f
    unsigned int pk0 = (unsigned int)f2b(p0[0]) | ((unsigned int)f2b(p0[1]) << 16);
    unsigned int pk1 = (unsigned int)f2b(p0[2]) | ((unsigned int)f2b(p0[3]) << 16);
    unsigned int pk2 = (unsigned int)f2b(p1[0]) | ((unsigned int)f2b(p1[1]) << 16);
    unsigned int pk3 = (unsigned int)f2b(p1[2]) | ((unsigned int)f2b(p1[3]) << 16);
    int prow = (w*16 + lr)*40;
    *reinterpret_cast<unsigned int*>(&Ps[prow + lg*4])          = pk0;
    *reinterpret_cast<unsigned int*>(&Ps[prow + lg*4 + 2])      = pk1;
    *reinterpret_cast<unsigned int*>(&Ps[prow + 16 + lg*4])     = pk2;
    *reinterpret_cast<unsigned int*>(&Ps[prow + 16 + lg*4 + 2]) = pk3;
    if (lg == 0) f_s[w*16 + lr] = f;

    __syncthreads();   // B1: Ps/f_s ready; Ks consumed

    // ---- prefetch next K tile (overlaps PV; drained at B2)
    if (j0 + 32 < jend) STAGE_K(j0 + 32);

    // ---- V fragments direct from global (fragment-order layout: 1KB coalesced/wave)
    const int jt = j0 >> 5;
    bfrag vf[6];
    #pragma unroll
    for (int dt=0;dt<6;++dt)
      vf[dt] = *reinterpret_cast<const bfrag*>(
          vg + (size_t)jt*12288 + (size_t)(w*6 + dt)*512 + lr*32 + lg*8);

    // ---- PV: warp owns d-cols w*96..w*96+95, all 64 q-rows
    bfrag pf[4];
    #pragma unroll
    for (int qt=0;qt<4;++qt)
      pf[qt] = *reinterpret_cast<const bfrag*>(&Ps[(qt*16+lr)*40 + lg*8]);
    #pragma unroll
    for (int qt=0;qt<4;++qt) {
      #pragma unroll
      for (int i=0;i<4;++i) {
        float frv = f_s[qt*16 + lg*4 + i];
        #pragma unroll
        for (int dt=0;dt<6;++dt) o[qt][dt][i] *= frv;
      }
    }
    __builtin_amdgcn_s_setprio(1);
    #pragma unroll
    for (int qt=0;qt<4;++qt)
      #pragma unroll
      for (int dt=0;dt<6;++dt)
        o[qt][dt] = MFMA(pf[qt], vf[dt], o[qt][dt]);
    __builtin_amdgcn_s_setprio(0);

    __syncthreads();   // B2: drains K prefetch; Ps consumed
  }
  #undef STAGE_K

  unsigned short* Op = Opart + (size_t)split*8192*384;
  #pragma unroll
  for (int qt=0;qt<4;++qt)
    #pragma unroll
    for (int dt=0;dt<6;++dt)
      #pragma unroll
      for (int i=0;i<4;++i)
        Op[(size_t)(qbase + qt*16 + lg*4 + i)*384 + w*96 + dt*16 + lr] = f2b(o[qt][dt][i]);
  if (lg == 0) {
    mpart[split*8192 + qbase + w*16 + lr] = m;
    lpart[split*8192 + qbase + w*16 + lr] = lsum;
  }
}

// per-row combine weights: cw[row][s] = exp(m_s - M) / L  (4 splits)
__global__ void k_cw(const float* __restrict__ mp, const float* __restrict__ lp,
                     float* __restrict__ cw)
{
  int r = blockIdx.x*256 + threadIdx.x;   // 8192
  float m0 = mp[r], m1 = mp[8192+r], m2 = mp[16384+r], m3 = mp[24576+r];
  float M = fmaxf(fmaxf(m0,m1), fmaxf(m2,m3));
  float w0 = __expf(m0-M), w1 = __expf(m1-M), w2 = __expf(m2-M), w3 = __expf(m3-M);
  float L = lp[r]*w0 + lp[8192+r]*w1 + lp[16384+r]*w2 + lp[24576+r]*w3;
  float inv = 1.f / L;
  float4 o4 = make_float4(w0*inv, w1*inv, w2*inv, w3*inv);
  *reinterpret_cast<float4*>(&cw[r*4]) = o4;
}

// ---------------- LN1 + SiLU + residual ----------------
__global__ __launch_bounds__(256) void k_ln1(const float* __restrict__ pre, const float* __restrict__ Ei,
                      const float* __restrict__ g, const float* __restrict__ b,
                      float* __restrict__ out)
{
  int row = blockIdx.x, c = threadIdx.x;
  float v = pre[(size_t)row*256 + c];
  float s1 = v, s2 = v*v;
  #pragma unroll
  for (int o1=32;o1;o1>>=1){ s1 += __shfl_down(s1,o1); s2 += __shfl_down(s2,o1); }
  __shared__ float a1[4], a2[4];
  if ((c&63)==0){ a1[c>>6] = s1; a2[c>>6] = s2; }
  __syncthreads();
  float S1 = a1[0]+a1[1]+a1[2]+a1[3], S2 = a2[0]+a2[1]+a2[2]+a2[3];
  float mean = S1*(1.f/256.f), var = S2*(1.f/256.f) - mean*mean;
  float y = (v-mean)*rsqrtf(var+1e-5f)*g[c] + b[c];
  float sig = 1.f/(1.f+__expf(-y));
  out[(size_t)row*256 + c] = y*sig + Ei[(size_t)row*256 + c];
}

// ---------------- edge kernels ----------------
// scores + per-block (256-edge) online max/sum partials per head
__global__ __launch_bounds__(256) void k_escore(const int* __restrict__ ei, const float* __restrict__ ea,
                         const float* __restrict__ SC, float* __restrict__ sc,
                         float* __restrict__ pm, float* __restrict__ ps)
{
  int e = blockIdx.x*256 + threadIdx.x;
  int s = ei[e], d = ei[131072 + e];
  float wv = ea[e];
  float4 ai = *reinterpret_cast<const float4*>(&SC[(size_t)d*8]);      // wi scores (x_i = dst)
  float4 aj = *reinterpret_cast<const float4*>(&SC[(size_t)s*8 + 4]);  // wj scores (x_j = src)
  float4 o4 = make_float4((ai.x+aj.x)*wv, (ai.y+aj.y)*wv, (ai.z+aj.z)*wv, (ai.w+aj.w)*wv);
  *reinterpret_cast<float4*>(&sc[e*4]) = o4;

  float sv[4] = {o4.x, o4.y, o4.z, o4.w};
  __shared__ float sm_[4][4], ss_[4][4];
  int lane = threadIdx.x & 63, wvid = threadIdx.x >> 6;
  #pragma unroll
  for (int h=0; h<4; ++h) {
    float m = sv[h], s2 = 1.f;
    #pragma unroll
    for (int o1=32;o1;o1>>=1) {
      float om = __shfl_xor(m,o1), os = __shfl_xor(s2,o1);
      float M2 = fmaxf(m,om);
      s2 = s2*__expf(m-M2) + os*__expf(om-M2);
      m = M2;
    }
    if (lane==0){ sm_[wvid][h]=m; ss_[wvid][h]=s2; }
  }
  __syncthreads();
  if (threadIdx.x < 4) {
    int h = threadIdx.x;
    float M = sm_[0][h], S = ss_[0][h];
    #pragma unroll
    for (int i=1;i<4;++i){
      float M2 = fmaxf(M, sm_[i][h]);
      S = S*__expf(M-M2) + ss_[i][h]*__expf(sm_[i][h]-M2);
      M = M2;
    }
    pm[blockIdx.x*4+h] = M; ps[blockIdx.x*4+h] = S;
  }
}

// combine 128 block-partials per (chunk, head)
__global__ __launch_bounds__(128) void k_cfin(const float* __restrict__ pm, const float* __restrict__ ps,
                                              float* __restrict__ mx, float* __restrict__ sm)
{
  int ch = blockIdx.x;          // c*4+h, 16 total
  int c = ch >> 2, h = ch & 3;
  int t = threadIdx.x;          // 128 partial blocks per chunk
  float M = pm[(c*128 + t)*4 + h], S = ps[(c*128 + t)*4 + h];
  int lane = t & 63;
  #pragma unroll
  for (int o1=32;o1;o1>>=1){
    float om = __shfl_xor(M,o1), os = __shfl_xor(S,o1);
    float M2 = fmaxf(M,om);
    S = S*__expf(M-M2) + os*__expf(om-M2);
    M = M2;
  }
  __shared__ float am[2], as[2];
  if (lane==0){ am[t>>6]=M; as[t>>6]=S; }
  __syncthreads();
  if (t==0){
    float M2 = fmaxf(am[0],am[1]);
    float Sf = as[0]*__expf(am[0]-M2) + as[1]*__expf(am[1]-M2);
    mx[ch]=M2; sm[ch]=Sf;
  }
}

// CSR gather-aggregate over bf16 transform rows; softmax applied inline (pnorm folded)
__global__ __launch_bounds__(128) void k_aggr(const int* __restrict__ off,
                      const int* __restrict__ elist, const int* __restrict__ ei,
                      const float* __restrict__ sc,
                      const float* __restrict__ mx, const float* __restrict__ sm,
                      const unsigned short* __restrict__ Tb, float* __restrict__ g)
{
  int n = blockIdx.x, d = threadIdx.x;
  int qb = off[n], qe = off[n+1];
  float acc = 0.f;
  for (int q = qb; q < qe; ++q) {
    int e = elist[q];
    int s = ei[e];
    int ch = (e >> 15) * 4;
    float4 sv = *reinterpret_cast<const float4*>(&sc[e*4]);
    float px = __expf(sv.x - mx[ch+0]) / sm[ch+0];
    float py = __expf(sv.y - mx[ch+1]) / sm[ch+1];
    float pz = __expf(sv.z - mx[ch+2]) / sm[ch+2];
    float pw = __expf(sv.w - mx[ch+3]) / sm[ch+3];
    const unsigned short* Tr = Tb + (size_t)s*512;
    acc += px*b2f(Tr[d]) + py*b2f(Tr[128+d]) + pz*b2f(Tr[256+d]) + pw*b2f(Tr[384+d]);
  }
  g[(size_t)n*128 + d] = acc;
}

// ---------------- final: skip1 GEMV + combine + LN2 ----------------
__global__ __launch_bounds__(128) void k_final(const float* __restrict__ g1, const float* __restrict__ aux,
                       const float* __restrict__ sw, const float* __restrict__ sb,
                       const float* __restrict__ lg2, const float* __restrict__ lb2,
                       float* __restrict__ out)
{
  int row = blockIdx.x, c = threadIdx.x;
  __shared__ float gr[128];
  float gv = g1[(size_t)row*128 + c];
  gr[c] = gv; __syncthreads();
  float s1 = sb[c];
  #pragma unroll 8
  for (int k=0;k<128;++k) s1 += gr[k]*sw[k*128 + c];
  float s0 = aux[(size_t)row*128 + c];
  float v = gv + 0.5f*(s0 + s1);
  float m1 = v, m2 = v*v;
  #pragma unroll
  for (int o1=32;o1;o1>>=1){ m1 += __shfl_down(m1,o1); m2 += __shfl_down(m2,o1); }
  __shared__ float a1[2], a2[2];
  if ((c&63)==0){ a1[c>>6]=m1; a2[c>>6]=m2; }
  __syncthreads();
  float S1 = a1[0]+a1[1], S2 = a2[0]+a2[1];
  float mean = S1*(1.f/128.f), var = S2*(1.f/128.f) - mean*mean;
  out[(size_t)row*128 + c] = (v-mean)*rsqrtf(var+1e-5f)*lg2[c] + lb2[c];
}

// ---------------- host launch ----------------
extern "C" void kernel_launch(void* const* d_in, const int* in_sizes, int n_in,
                              void* d_out, int out_size, void* d_ws, size_t ws_size,
                              hipStream_t stream)
{
  const int*   ids    = (const int*)  d_in[0];
  const float* x      = (const float*)d_in[1];
  const float* ea     = (const float*)d_in[2];
  const int*   eidx   = (const int*)  d_in[3];
  const float* embed  = (const float*)d_in[4];
  const float* qkv_w  = (const float*)d_in[5];
  const float* qkv_b  = (const float*)d_in[6];
  const float* proj_w = (const float*)d_in[7];
  const float* proj_b = (const float*)d_in[8];
  const float* fuse_w = (const float*)d_in[9];
  const float* fuse_b = (const float*)d_in[10];
  const float* ln1_g  = (const float*)d_in[11];
  const float* ln1_b  = (const float*)d_in[12];
  const float* wi0 = (const float*)d_in[13]; const float* bi0 = (const float*)d_in[14];
  const float* wj0 = (const float*)d_in[15]; const float* bj0 = (const float*)d_in[16];
  const float* wt0 = (const float*)d_in[17]; const float* bt0 = (const float*)d_in[18];
  const float* attn0 = (const float*)d_in[19];
  const float* sk0w = (const float*)d_in[20]; const float* sk0b = (const float*)d_in[21];
  const float* wi1 = (const float*)d_in[22]; const float* bi1 = (const float*)d_in[23];
  const float* wj1 = (const float*)d_in[24]; const float* bj1 = (const float*)d_in[25];
  const float* wt1 = (const float*)d_in[26]; const float* bt1 = (const float*)d_in[27];
  const float* attn1 = (const float*)d_in[28];
  const float* sk1w = (const float*)d_in[29]; const float* sk1b = (const float*)d_in[30];
  const float* ln2_g = (const float*)d_in[31]; const float* ln2_b = (const float*)d_in[32];

  char* ws = (char*)d_ws;
  const size_t MBy = (size_t)1 << 20;

  // static area (0..2MB), zeroed each call
  unsigned short* BtQKV  = (unsigned short*)(ws + 0);
  unsigned short* BtW2   = (unsigned short*)(ws + 589824);   // 196608 B
  float* biasW2 = (float*)(ws + 884736);                     // 1024 B
  unsigned short* BtT0   = (unsigned short*)(ws + 1081344);  // 640x256x2
  unsigned short* BtT1   = (unsigned short*)(ws + 1409024);  // 768x128x2
  float* biasT0 = (float*)(ws + 1605632);
  float* biasT1 = (float*)(ws + 1608192);
  float* wsum   = (float*)(ws + 1611264);
  float* mxb    = (float*)(ws + 1615872);
  float* smb    = (float*)(ws + 1615936);
  int* deg    = (int*)(ws + 1703936);
  int* cursor = (int*)(ws + 1736704);
  int* off    = (int*)(ws + 1769472);
  float* cw   = (float*)(ws + 1806336);                      // 131072 B -> ends 1937408
  float* pm   = (float*)(ws + 1937408);                      // 8192 B
  float* ps   = (float*)(ws + 1945600);                      // 8192 B

  float* Ei   = (float*)(ws + 2*MBy);                   // 2..10
  unsigned short* qb = (unsigned short*)(ws + 10*MBy);  // 10..16.3
  unsigned short* kb = (unsigned short*)(ws + 17*MBy);  // 17..23.3 (row-major)
  unsigned short* vb = (unsigned short*)(ws + 24*MBy);  // 24..30.3 (fragment-order)
  unsigned short* Opart = (unsigned short*)(ws + 31*MBy);  // 31..55 (4 x 6MB bf16 partials)
  float* mpart = (float*)(ws + 55*MBy);                 // 128KB
  float* lpart = (float*)(ws + 55*MBy + 131072);        // 128KB -> ends 55.25MB
  float* pre  = (float*)(ws + 10*MBy);                  // over qb (dead after flash)
  float* emb0 = (float*)(ws + 31*MBy);                  // over Opart head (dead after mode-2)
  unsigned short* TCb0 = (unsigned short*)(ws + 39*MBy);// 39..47 (bf16 8192x512)
  float* SCb0 = (float*)(ws + 47*MBy);                  // 256KB
  float* SCb1 = (float*)(ws + 47*MBy + 262144);         // 256KB -> 47.5
  float* AUX  = (float*)(ws + 47*MBy + 524288);         // 47.5..51.5 (f32 8192x128)
  float* sc0  = (float*)(ws + 52*MBy);                  // 52..54
  float* sc1  = (float*)(ws + 54*MBy);                  // 54..56 (mpart/lpart dead by then)
  unsigned short* TCb1 = (unsigned short*)(ws + 18*MBy);// 18..26 (kb/vb dead)
  float* g0   = (float*)(ws + 2*MBy);                   // over Ei (dead after ln1)
  float* g1   = (float*)(ws + 6*MBy);                   // over Ei tail
  int* elist  = (int*)(ws + 62*MBy);                    // 62..62.5

  float* out = (float*)d_out;

  hipMemsetAsync(ws, 0, 2*MBy, stream);

  // prep: weight transforms + Ei gather + output copy (embed + ids)
  k_prep<<<16939, 256, 0, stream>>>(qkv_w, proj_w, proj_b, fuse_w, fuse_b,
                                    wt0, wt1, sk0w,
                                    wi0, bi0, wj0, bj0, wi1, bi1, wj1, bj1,
                                    attn0, attn1, bt0, bt1, sk0b, embed, ids,
                                    BtQKV, BtW2, BtT0, BtT1,
                                    biasW2, biasT0, biasT1, wsum, Ei, out);
  k_deg<<<512, 256, 0, stream>>>(eidx, deg);
  k_scan<<<1, 1024, 0, stream>>>(deg, off, cursor);
  k_fill<<<512, 256, 0, stream>>>(eidx, cursor, elist);

  // QKV GEMM with rank-1 x term, packing q(scaled)/k row-major + v fragment-order bf16
  k_gemm<<<dim3(9,64), 256, 0, stream>>>(Ei, 256, BtQKV, 256, qkv_b, nullptr, 0, 1,
                                         x, wsum, qb, kb, vb, nullptr, nullptr,
                                         nullptr, 0);
  k_flash<<<512, 256, 0, stream>>>(qb, kb, vb, Opart, mpart, lpart);
  k_cw<<<32, 256, 0, stream>>>(mpart, lpart, cw);

  // fused (combine -> att) @ (proj_w@fuse_w) + bias2  ->  pre
  k_gemm<<<dim3(2,64), 256, 0, stream>>>(nullptr, 0, BtW2, 384, biasW2, pre, 256, 2,
                                         nullptr, nullptr, nullptr, nullptr, nullptr,
                                         Opart, cw, nullptr, 0);
  k_ln1<<<8192, 256, 0, stream>>>(pre, Ei, ln1_g, ln1_b, emb0);

  // WGAT layer 0: transform -> bf16 TCb0, scores -> SCb0
  k_gemm<<<dim3(5,64), 256, 0, stream>>>(emb0, 256, BtT0, 256, biasT0, SCb0, 0, 3,
                                         nullptr, nullptr, TCb0, nullptr, nullptr,
                                         nullptr, nullptr, AUX, 520);
  k_escore<<<512, 256, 0, stream>>>(eidx, ea, SCb0, sc0, pm, ps);
  k_cfin<<<16, 128, 0, stream>>>(pm, ps, mxb, smb);
  k_aggr<<<8192, 128, 0, stream>>>(off, elist, eidx, sc0, mxb, smb, TCb0, g0);

  // WGAT layer 1: transform -> bf16 TCb1, scores -> SCb1, skip0 -> AUX
  k_gemm<<<dim3(6,64), 256, 0, stream>>>(g0, 128, BtT1, 128, biasT1, SCb1, 0, 3,
                                         nullptr, nullptr, TCb1, nullptr, nullptr,
                                         nullptr, nullptr, AUX, 648);
  k_escore<<<512, 256, 0, stream>>>(eidx, ea, SCb1, sc1, pm, ps);
  k_cfin<<<16, 128, 0, stream>>>(pm, ps, mxb, smb);
  k_aggr<<<8192, 128, 0, stream>>>(off, elist, eidx, sc1, mxb, smb, TCb1, g1);

  k_final<<<8192, 128, 0, stream>>>(g1, AUX, sk1w, sk1b, ln2_g, ln2_b, out);
}

// Round 14
// 424.702 us; speedup vs baseline: 1.4651x; 1.0493x over previous
//
#include <hip/hip_runtime.h>

typedef __attribute__((ext_vector_type(8))) short bfrag;   // 8 x bf16
typedef __attribute__((ext_vector_type(4))) float f4;

#define MFMA(a,b,c) __builtin_amdgcn_mfma_f32_16x16x32_bf16(a,b,c,0,0,0)

__device__ __forceinline__ unsigned short f2b(float x){
  union { float f; unsigned int u; } v; v.f = x;
  unsigned int r = v.u + 0x7fffu + ((v.u >> 16) & 1u);
  return (unsigned short)(r >> 16);
}
__device__ __forceinline__ float b2f(unsigned short h){
  union { unsigned int u; float f; } v; v.u = ((unsigned int)h) << 16;
  return v.f;
}

// ---------------- merged prep kernel (weights + gathers + output copy) ----------------
__global__ __launch_bounds__(256) void k_prep(
    const float* __restrict__ qkv_w, const float* __restrict__ proj_w,
    const float* __restrict__ proj_b, const float* __restrict__ fuse_w,
    const float* __restrict__ fuse_b,
    const float* __restrict__ wt0,
    const float* __restrict__ wt1, const float* __restrict__ sk0w,
    const float* __restrict__ wi0, const float* __restrict__ bi0,
    const float* __restrict__ wj0, const float* __restrict__ bj0,
    const float* __restrict__ wi1, const float* __restrict__ bi1,
    const float* __restrict__ wj1, const float* __restrict__ bj1,
    const float* __restrict__ attn0, const float* __restrict__ attn1,
    const float* __restrict__ bt0, const float* __restrict__ bt1,
    const float* __restrict__ sk0b,
    const float* __restrict__ embed, const int* __restrict__ ids,
    unsigned short* __restrict__ BtQKV, unsigned short* __restrict__ BtW2,
    unsigned short* __restrict__ BtT0, unsigned short* __restrict__ BtT1,
    float* __restrict__ biasW2,
    float* __restrict__ biasT0, float* __restrict__ biasT1,
    float* __restrict__ wsum, float* __restrict__ Ei,
    float* __restrict__ out)
{
  int b = blockIdx.x, t = threadIdx.x;
  if (b < 1152) {            // QKV weight rows 128..383, transpose to [1152][256]
    int idx = b*256 + t; int k = idx/1152, n = idx - k*1152;
    BtQKV[(size_t)n*256 + k] = f2b(qkv_w[128*1152 + idx]);
  } else if (b < 1536) {     // W2 = proj_w @ fuse_w  -> Bt layout [256][384]
    int k = b - 1152;        // 0..383
    float s = 0.f;
    for (int j = 0; j < 384; ++j) s += proj_w[(size_t)k*384 + j] * fuse_w[(size_t)j*256 + t];
    BtW2[(size_t)t*384 + k] = f2b(s);
  } else if (b == 1536) {    // bias2 = proj_b @ fuse_w + fuse_b
    float s = fuse_b[t];
    for (int j = 0; j < 384; ++j) s += proj_b[j] * fuse_w[(size_t)j*256 + t];
    biasW2[t] = s;
  } else if (b < 2049) {     // wt0 256x512
    int idx = (b-1537)*256 + t; int k = idx/512, n = idx - k*512;
    BtT0[(size_t)n*256 + k] = f2b(wt0[idx]);
  } else if (b < 2305) {     // wt1 128x512
    int idx = (b-2049)*256 + t; int k = idx/512, n = idx - k*512;
    BtT1[(size_t)n*128 + k] = f2b(wt1[idx]);
  } else if (b < 2369) {     // sk0w 128x128 -> rows 520..647 of BtT1
    int idx = (b-2305)*256 + t; int k = idx/128, n = idx - k*128;
    BtT1[(size_t)(520+n)*128 + k] = f2b(sk0w[idx]);
  } else if (b < 2373) {     // attnred wi0 (K=256) -> BtT0 rows 512..515
    int idx = (b-2369)*256 + t;
    int h = idx >> 8, k = idx & 255;
    float s = 0.f;
    for (int d = 0; d < 128; ++d) s += wi0[(size_t)k*512 + h*128 + d] * attn0[h*128 + d];
    BtT0[(size_t)(512 + h)*256 + k] = f2b(s);
    if (idx < 4) {
      float sb = 0.f;
      for (int d = 0; d < 128; ++d) sb += bi0[idx*128 + d] * attn0[idx*128 + d];
      biasT0[512 + idx] = sb;
    }
  } else if (b < 2377) {     // attnred wj0 -> BtT0 rows 516..519
    int idx = (b-2373)*256 + t;
    int h = idx >> 8, k = idx & 255;
    float s = 0.f;
    for (int d = 0; d < 128; ++d) s += wj0[(size_t)k*512 + h*128 + d] * attn0[h*128 + d];
    BtT0[(size_t)(516 + h)*256 + k] = f2b(s);
    if (idx < 4) {
      float sb = 0.f;
      for (int d = 0; d < 128; ++d) sb += bj0[idx*128 + d] * attn0[idx*128 + d];
      biasT0[516 + idx] = sb;
    }
  } else if (b < 2379) {     // attnred wi1 (K=128) -> BtT1 rows 512..515
    int idx = (b-2377)*256 + t;
    int h = idx >> 7, k = idx & 127;
    float s = 0.f;
    for (int d = 0; d < 128; ++d) s += wi1[(size_t)k*512 + h*128 + d] * attn1[h*128 + d];
    BtT1[(size_t)(512 + h)*128 + k] = f2b(s);
    if (idx < 4) {
      float sb = 0.f;
      for (int d = 0; d < 128; ++d) sb += bi1[idx*128 + d] * attn1[idx*128 + d];
      biasT1[512 + idx] = sb;
    }
  } else if (b < 2381) {     // attnred wj1 -> BtT1 rows 516..519
    int idx = (b-2379)*256 + t;
    int h = idx >> 7, k = idx & 127;
    float s = 0.f;
    for (int d = 0; d < 128; ++d) s += wj1[(size_t)k*512 + h*128 + d] * attn1[h*128 + d];
    BtT1[(size_t)(516 + h)*128 + k] = f2b(s);
    if (idx < 4) {
      float sb = 0.f;
      for (int d = 0; d < 128; ++d) sb += bj1[idx*128 + d] * attn1[idx*128 + d];
      biasT1[516 + idx] = sb;
    }
  } else if (b < 2383) {     // copy bt0 -> biasT0[0..511]
    int idx = (b-2381)*256 + t; biasT0[idx] = bt0[idx];
  } else if (b < 2385) {     // copy bt1 -> biasT1[0..511]
    int idx = (b-2383)*256 + t; biasT1[idx] = bt1[idx];
  } else if (b == 2385) {    // copy sk0b -> biasT1[520..647]
    if (t < 128) biasT1[520 + t] = sk0b[t];
  } else if (b < 2391) {     // wsum
    int n = (b-2386)*256 + t;
    if (n < 1152) {
      float s = 0.f;
      for (int k = 0; k < 128; ++k) s += qkv_w[(size_t)k*1152 + n];
      wsum[n] = s;
    }
  } else if (b < 4439) {     // gather Ei (float4): 524288 elems
    int idx = (b-2391)*256 + t;
    int n = idx >> 6, c4 = idx & 63;
    reinterpret_cast<float4*>(Ei)[idx] =
        reinterpret_cast<const float4*>(embed + (size_t)ids[n]*256)[c4];
  } else {                   // output copy: embed -> out[1048576..], ids -> tail
    int i = (b-4439)*256 + t;
    if (i < 3200000)
      reinterpret_cast<float4*>(out)[262144 + i] = reinterpret_cast<const float4*>(embed)[i];
    if (i < 8192) out[13848576 + i] = (float)ids[i];
  }
}

// ---------------- CSR build ----------------
__global__ void k_deg(const int* __restrict__ ei, int* __restrict__ deg){
  int e = blockIdx.x*256 + threadIdx.x; if (e >= 131072) return;
  atomicAdd(&deg[ei[131072 + e]], 1);
}

__global__ __launch_bounds__(1024) void k_scan(const int* __restrict__ deg,
                                               int* __restrict__ off, int* __restrict__ cursor){
  int t = threadIdx.x;
  int v[8]; int s = 0;
  #pragma unroll
  for (int i=0;i<8;++i){ v[i] = s; s += deg[t*8 + i]; }
  int lane = t & 63, w = t >> 6;
  int si = s;
  for (int o=1;o<64;o<<=1){ int u = __shfl_up(si, o); if (lane >= o) si += u; }
  __shared__ int wsum[16];
  if (lane == 63) wsum[w] = si;
  __syncthreads();
  if (t < 16) {
    int x = wsum[t];
    for (int o=1;o<16;o<<=1){ int u = __shfl_up(x, o); if (t >= o) x += u; }
    wsum[t] = x;
  }
  __syncthreads();
  int wbase = (w == 0) ? 0 : wsum[w-1];
  int base = wbase + (si - s);
  #pragma unroll
  for (int i=0;i<8;++i){ int o2 = base + v[i]; off[t*8+i] = o2; cursor[t*8+i] = o2; }
  if (t == 1023) off[8192] = wbase + si;
}

__global__ void k_fill(const int* __restrict__ ei, int* __restrict__ cursor,
                       int* __restrict__ elist){
  int e = blockIdx.x*256 + threadIdx.x; if (e >= 131072) return;
  int d = ei[131072 + e];
  int slot = atomicAdd(&cursor[d], 1);
  elist[slot] = e;
}

// ---------------- GEMM: C/outputs = A[M,K]@Bt[N,K]^T + bias ----------------
// mode 0: A f32 -> C f32.  mode 1: QKV pack epilogue (K row-major, V fragment-order).
// mode 2: A = combine of 4 bf16 O-partials -> C f32.
// mode 3: WGAT epilogue: col<512 -> tb bf16; 512..519 -> scb f32; 520..ncols -> aux f32.
__global__ __launch_bounds__(256) void k_gemm(
    const float* __restrict__ A, int lda,
    const unsigned short* __restrict__ Bt, int K,
    const float* __restrict__ bias,
    float* __restrict__ C, int ldc, int mode,
    const float* __restrict__ xv, const float* __restrict__ wsum,
    unsigned short* __restrict__ qO, unsigned short* __restrict__ kO,
    unsigned short* __restrict__ vO,
    const unsigned short* __restrict__ opA, const float* __restrict__ cw,
    float* __restrict__ aux, int ncols)
{
  __shared__ unsigned short As[128*40];
  __shared__ unsigned short Bs[128*40];
  const int t = threadIdx.x;
  const int wid = t >> 6, l = t & 63;
  const int lr = l & 15, lg = l >> 4;
  const int arow0 = blockIdx.y*128, bn0 = blockIdx.x*128;
  const int wr = (wid >> 1)*64, wc = (wid & 1)*64;
  f4 zero = {0.f,0.f,0.f,0.f};
  f4 acc[4][4];
  #pragma unroll
  for (int i=0;i<4;++i)
    #pragma unroll
    for (int j=0;j<4;++j) acc[i][j] = zero;

  for (int k0 = 0; k0 < K; k0 += 32) {
    #pragma unroll
    for (int p=0;p<4;++p) {
      int row = p*32 + (t>>3);
      int c4  = (t&7)*4;
      ushort4 h4;
      if (mode == 2) {
        const float* w4 = &cw[(arow0+row)*4];
        float a0=0.f,a1=0.f,a2=0.f,a3=0.f;
        #pragma unroll
        for (int s=0;s<4;++s) {
          ushort4 u = *reinterpret_cast<const ushort4*>(
              opA + (size_t)s*3145728 + (size_t)(arow0+row)*384 + k0 + c4);
          float wv = w4[s];
          a0 += b2f(u.x)*wv; a1 += b2f(u.y)*wv; a2 += b2f(u.z)*wv; a3 += b2f(u.w)*wv;
        }
        h4.x = f2b(a0); h4.y = f2b(a1); h4.z = f2b(a2); h4.w = f2b(a3);
      } else {
        float4 v = *reinterpret_cast<const float4*>(A + (size_t)(arow0+row)*lda + k0 + c4);
        h4.x = f2b(v.x); h4.y = f2b(v.y); h4.z = f2b(v.z); h4.w = f2b(v.w);
      }
      *reinterpret_cast<ushort4*>(&As[row*40 + c4]) = h4;
    }
    #pragma unroll
    for (int p=0;p<2;++p) {
      int n  = p*64 + (t>>2);
      int c8 = (t&3)*8;
      int4 v = *reinterpret_cast<const int4*>(Bt + (size_t)(bn0+n)*K + k0 + c8);
      *reinterpret_cast<int4*>(&Bs[n*40 + c8]) = v;
    }
    __syncthreads();
    bfrag af[4], bfm[4];
    #pragma unroll
    for (int mi=0;mi<4;++mi) af[mi] = *reinterpret_cast<const bfrag*>(&As[(wr+mi*16+lr)*40 + lg*8]);
    #pragma unroll
    for (int ni=0;ni<4;++ni) bfm[ni] = *reinterpret_cast<const bfrag*>(&Bs[(wc+ni*16+lr)*40 + lg*8]);
    #pragma unroll
    for (int mi=0;mi<4;++mi)
      #pragma unroll
      for (int ni=0;ni<4;++ni)
        acc[mi][ni] = MFMA(af[mi], bfm[ni], acc[mi][ni]);
    __syncthreads();
  }
  #pragma unroll
  for (int mi=0;mi<4;++mi) {
    #pragma unroll
    for (int ni=0;ni<4;++ni) {
      int col = bn0 + wc + ni*16 + lr;
      float bv = bias[col];
      float wsv = (mode==1) ? wsum[col] : 0.f;
      #pragma unroll
      for (int i=0;i<4;++i) {
        int row = arow0 + wr + mi*16 + lg*4 + i;
        float val = acc[mi][ni][i] + bv;
        if (mode == 1) {
          val += xv[row]*wsv;
          if (col < 384) val *= 0.05103103631f;   // fold attention scale into Q
          unsigned short hv = f2b(val);
          if (col < 384)      qO[(size_t)row*384 + col] = hv;
          else if (col < 768) kO[(size_t)row*384 + col - 384] = hv;
          else {
            // V in MFMA B-frag order: V'[j>>5][d>>4][d&15][(j&31)>>3][j&7]
            int d = col - 768, j = row;
            size_t vidx = (size_t)(j >> 5)*12288 + (size_t)(d >> 4)*512
                        + (size_t)(d & 15)*32 + (size_t)((j & 31) >> 3)*8 + (j & 7);
            vO[vidx] = hv;
          }
        } else if (mode == 3) {
          if (col < 512)      qO[(size_t)row*512 + col] = f2b(val);
          else if (col < 520) C[(size_t)row*8 + col - 512] = val;
          else if (col < ncols) aux[(size_t)row*128 + col - 520] = val;
        } else {
          C[(size_t)row*ldc + col] = val;
        }
      }
    }
  }
}

// ---------------- flash attention (round-8 proven best): KSPLIT=4, K staged in LDS
//   via global_load_lds + XOR swizzle, V direct-from-global (fragment order),
//   lane-local softmax + defer-max, 2 barriers/iter ----------------
__global__ __launch_bounds__(256,2) void k_flash(
    const unsigned short* __restrict__ qg,
    const unsigned short* __restrict__ kg,
    const unsigned short* __restrict__ vg,
    unsigned short* __restrict__ Opart, float* __restrict__ mpart, float* __restrict__ lpart)
{
  __shared__ unsigned short Ks[32*384];      // K tile, XOR-swizzled 16B units
  __shared__ unsigned short Ps[64*40];       // P tile [q][k] bf16
  __shared__ float f_s[64];

  const int t = threadIdx.x;
  const int w = t >> 6, l = t & 63;
  const int lr = l & 15, lg = l >> 4;
  const int qbi = blockIdx.x >> 2, split = blockIdx.x & 3;
  const int qbase = qbi * 64;

  #define STAGE_K(JJ) do { \
    _Pragma("unroll") \
    for (int p_=0;p_<6;++p_) { \
      int idx_ = p_*256 + t; \
      int row_ = idx_ / 48, uu_ = idx_ - row_*48; \
      int ug_ = uu_ ^ (row_ & 7); \
      const unsigned short* gp_ = kg + (size_t)((JJ) + row_)*384 + ug_*8; \
      __builtin_amdgcn_global_load_lds((const __attribute__((address_space(1))) void*)gp_, \
          (__attribute__((address_space(3))) void*)&Ks[idx_*8], 16, 0, 0); \
    } } while(0)

  bfrag qf[12];
  #pragma unroll
  for (int kk=0;kk<12;++kk)
    qf[kk] = *reinterpret_cast<const bfrag*>(qg + (size_t)(qbase + w*16 + lr)*384 + kk*32 + lg*8);

  f4 zero = {0.f,0.f,0.f,0.f};
  f4 o[4][6];
  #pragma unroll
  for (int a=0;a<4;++a)
    #pragma unroll
    for (int b=0;b<6;++b) o[a][b] = zero;

  float m = -3e38f, lsum = 0.f;
  const int j0beg = split*2048, jend = j0beg + 2048;

  STAGE_K(j0beg);
  __syncthreads();

  for (int j0 = j0beg; j0 < jend; j0 += 32) {
    // ---- QK^T (swapped): A = K rows from LDS, B = Q regs -> S[key][q=lr]
    f4 s0 = zero, s1 = zero;
    __builtin_amdgcn_s_setprio(1);
    #pragma unroll
    for (int kk=0;kk<12;++kk) {
      int su = ((kk*4 + lg) ^ (lr & 7)) * 8;
      bfrag k0 = *reinterpret_cast<const bfrag*>(&Ks[lr*384 + su]);
      bfrag k1 = *reinterpret_cast<const bfrag*>(&Ks[(16+lr)*384 + su]);
      s0 = MFMA(k0, qf[kk], s0);
      s1 = MFMA(k1, qf[kk], s1);
    }
    __builtin_amdgcn_s_setprio(0);

    // ---- lane-local online softmax with defer-max (THR=8)
    float mt = fmaxf(fmaxf(fmaxf(s0[0],s0[1]),fmaxf(s0[2],s0[3])),
                     fmaxf(fmaxf(s1[0],s1[1]),fmaxf(s1[2],s1[3])));
    mt = fmaxf(mt, __shfl_xor(mt,16));
    mt = fmaxf(mt, __shfl_xor(mt,32));
    bool grew = mt > m + 8.f;
    bool doresc = __any(grew);
    float mn = doresc ? fmaxf(m, mt) : m;
    float p0[4], p1[4];
    float sum = 0.f;
    #pragma unroll
    for (int i=0;i<4;++i) {
      p0[i] = __expf(s0[i]-mn); p1[i] = __expf(s1[i]-mn);
      sum += p0[i] + p1[i];
    }
    sum += __shfl_xor(sum,16);
    sum += __shfl_xor(sum,32);
    float f = 1.f;
    if (doresc) {
      f = __expf(m - mn);
      lsum = lsum * f + sum;
      m = mn;
    } else {
      lsum += sum;
    }

    // ---- write P tile + f
    unsigned int pk0 = (unsigned int)f2b(p0[0]) | ((unsigned int)f2b(p0[1]) << 16);
    unsigned int pk1 = (unsigned int)f2b(p0[2]) | ((unsigned int)f2b(p0[3]) << 16);
    unsigned int pk2 = (unsigned int)f2b(p1[0]) | ((unsigned int)f2b(p1[1]) << 16);
    unsigned int pk3 = (unsigned int)f2b(p1[2]) | ((unsigned int)f2b(p1[3]) << 16);
    int prow = (w*16 + lr)*40;
    *reinterpret_cast<unsigned int*>(&Ps[prow + lg*4])          = pk0;
    *reinterpret_cast<unsigned int*>(&Ps[prow + lg*4 + 2])      = pk1;
    *reinterpret_cast<unsigned int*>(&Ps[prow + 16 + lg*4])     = pk2;
    *reinterpret_cast<unsigned int*>(&Ps[prow + 16 + lg*4 + 2]) = pk3;
    if (lg == 0) f_s[w*16 + lr] = f;

    __syncthreads();   // B1: Ps/f_s ready; Ks consumed

    // ---- prefetch next K tile (overlaps PV; drained at B2)
    if (j0 + 32 < jend) STAGE_K(j0 + 32);

    // ---- V fragments direct from global (fragment-order layout: 1KB coalesced/wave)
    const int jt = j0 >> 5;
    bfrag vf[6];
    #pragma unroll
    for (int dt=0;dt<6;++dt)
      vf[dt] = *reinterpret_cast<const bfrag*>(
          vg + (size_t)jt*12288 + (size_t)(w*6 + dt)*512 + lr*32 + lg*8);

    // ---- PV: warp owns d-cols w*96..w*96+95, all 64 q-rows
    bfrag pf[4];
    #pragma unroll
    for (int qt=0;qt<4;++qt)
      pf[qt] = *reinterpret_cast<const bfrag*>(&Ps[(qt*16+lr)*40 + lg*8]);
    #pragma unroll
    for (int qt=0;qt<4;++qt) {
      #pragma unroll
      for (int i=0;i<4;++i) {
        float frv = f_s[qt*16 + lg*4 + i];
        #pragma unroll
        for (int dt=0;dt<6;++dt) o[qt][dt][i] *= frv;
      }
    }
    __builtin_amdgcn_s_setprio(1);
    #pragma unroll
    for (int qt=0;qt<4;++qt)
      #pragma unroll
      for (int dt=0;dt<6;++dt)
        o[qt][dt] = MFMA(pf[qt], vf[dt], o[qt][dt]);
    __builtin_amdgcn_s_setprio(0);

    __syncthreads();   // B2: drains K prefetch; Ps consumed
  }
  #undef STAGE_K

  unsigned short* Op = Opart + (size_t)split*8192*384;
  #pragma unroll
  for (int qt=0;qt<4;++qt)
    #pragma unroll
    for (int dt=0;dt<6;++dt)
      #pragma unroll
      for (int i=0;i<4;++i)
        Op[(size_t)(qbase + qt*16 + lg*4 + i)*384 + w*96 + dt*16 + lr] = f2b(o[qt][dt][i]);
  if (lg == 0) {
    mpart[split*8192 + qbase + w*16 + lr] = m;
    lpart[split*8192 + qbase + w*16 + lr] = lsum;
  }
}

// per-row combine weights: cw[row][s] = exp(m_s - M) / L  (4 splits)
__global__ void k_cw(const float* __restrict__ mp, const float* __restrict__ lp,
                     float* __restrict__ cw)
{
  int r = blockIdx.x*256 + threadIdx.x;   // 8192
  float m0 = mp[r], m1 = mp[8192+r], m2 = mp[16384+r], m3 = mp[24576+r];
  float M = fmaxf(fmaxf(m0,m1), fmaxf(m2,m3));
  float w0 = __expf(m0-M), w1 = __expf(m1-M), w2 = __expf(m2-M), w3 = __expf(m3-M);
  float L = lp[r]*w0 + lp[8192+r]*w1 + lp[16384+r]*w2 + lp[24576+r]*w3;
  float inv = 1.f / L;
  float4 o4 = make_float4(w0*inv, w1*inv, w2*inv, w3*inv);
  *reinterpret_cast<float4*>(&cw[r*4]) = o4;
}

// ---------------- LN1 + SiLU + residual ----------------
__global__ __launch_bounds__(256) void k_ln1(const float* __restrict__ pre, const float* __restrict__ Ei,
                      const float* __restrict__ g, const float* __restrict__ b,
                      float* __restrict__ out)
{
  int row = blockIdx.x, c = threadIdx.x;
  float v = pre[(size_t)row*256 + c];
  float s1 = v, s2 = v*v;
  #pragma unroll
  for (int o1=32;o1;o1>>=1){ s1 += __shfl_down(s1,o1); s2 += __shfl_down(s2,o1); }
  __shared__ float a1[4], a2[4];
  if ((c&63)==0){ a1[c>>6] = s1; a2[c>>6] = s2; }
  __syncthreads();
  float S1 = a1[0]+a1[1]+a1[2]+a1[3], S2 = a2[0]+a2[1]+a2[2]+a2[3];
  float mean = S1*(1.f/256.f), var = S2*(1.f/256.f) - mean*mean;
  float y = (v-mean)*rsqrtf(var+1e-5f)*g[c] + b[c];
  float sig = 1.f/(1.f+__expf(-y));
  out[(size_t)row*256 + c] = y*sig + Ei[(size_t)row*256 + c];
}

// ---------------- edge kernels ----------------
// scores + per-block (256-edge) online max/sum partials per head
__global__ __launch_bounds__(256) void k_escore(const int* __restrict__ ei, const float* __restrict__ ea,
                         const float* __restrict__ SC, float* __restrict__ sc,
                         float* __restrict__ pm, float* __restrict__ ps)
{
  int e = blockIdx.x*256 + threadIdx.x;
  int s = ei[e], d = ei[131072 + e];
  float wv = ea[e];
  float4 ai = *reinterpret_cast<const float4*>(&SC[(size_t)d*8]);      // wi scores (x_i = dst)
  float4 aj = *reinterpret_cast<const float4*>(&SC[(size_t)s*8 + 4]);  // wj scores (x_j = src)
  float4 o4 = make_float4((ai.x+aj.x)*wv, (ai.y+aj.y)*wv, (ai.z+aj.z)*wv, (ai.w+aj.w)*wv);
  *reinterpret_cast<float4*>(&sc[e*4]) = o4;

  float sv[4] = {o4.x, o4.y, o4.z, o4.w};
  __shared__ float sm_[4][4], ss_[4][4];
  int lane = threadIdx.x & 63, wvid = threadIdx.x >> 6;
  #pragma unroll
  for (int h=0; h<4; ++h) {
    float m = sv[h], s2 = 1.f;
    #pragma unroll
    for (int o1=32;o1;o1>>=1) {
      float om = __shfl_xor(m,o1), os = __shfl_xor(s2,o1);
      float M2 = fmaxf(m,om);
      s2 = s2*__expf(m-M2) + os*__expf(om-M2);
      m = M2;
    }
    if (lane==0){ sm_[wvid][h]=m; ss_[wvid][h]=s2; }
  }
  __syncthreads();
  if (threadIdx.x < 4) {
    int h = threadIdx.x;
    float M = sm_[0][h], S = ss_[0][h];
    #pragma unroll
    for (int i=1;i<4;++i){
      float M2 = fmaxf(M, sm_[i][h]);
      S = S*__expf(M-M2) + ss_[i][h]*__expf(sm_[i][h]-M2);
      M = M2;
    }
    pm[blockIdx.x*4+h] = M; ps[blockIdx.x*4+h] = S;
  }
}

// combine 128 block-partials per (chunk, head); store max and RECIPROCAL of sum
__global__ __launch_bounds__(128) void k_cfin(const float* __restrict__ pm, const float* __restrict__ ps,
                                              float* __restrict__ mx, float* __restrict__ sm)
{
  int ch = blockIdx.x;          // c*4+h, 16 total
  int c = ch >> 2, h = ch & 3;
  int t = threadIdx.x;          // 128 partial blocks per chunk
  float M = pm[(c*128 + t)*4 + h], S = ps[(c*128 + t)*4 + h];
  int lane = t & 63;
  #pragma unroll
  for (int o1=32;o1;o1>>=1){
    float om = __shfl_xor(M,o1), os = __shfl_xor(S,o1);
    float M2 = fmaxf(M,om);
    S = S*__expf(M-M2) + os*__expf(om-M2);
    M = M2;
  }
  __shared__ float am[2], as[2];
  if (lane==0){ am[t>>6]=M; as[t>>6]=S; }
  __syncthreads();
  if (t==0){
    float M2 = fmaxf(am[0],am[1]);
    float Sf = as[0]*__expf(am[0]-M2) + as[1]*__expf(am[1]-M2);
    mx[ch]=M2; sm[ch]=1.f/Sf;
  }
}

// normalize scores -> probabilities (exp once per edge-head)
__global__ void k_pnorm(float* __restrict__ sc, const float* __restrict__ mx,
                        const float* __restrict__ sm)
{
  int i = blockIdx.x*256 + threadIdx.x;   // 524288 exactly
  int e = i >> 2, h = i & 3;
  int ch = (e >> 15)*4 + h;
  sc[i] = __expf(sc[i] - mx[ch]) * sm[ch];
}

// CSR gather-aggregate over bf16 transform rows
__global__ __launch_bounds__(128) void k_aggr(const int* __restrict__ off,
                      const int* __restrict__ elist, const int* __restrict__ ei,
                      const float* __restrict__ sc,
                      const unsigned short* __restrict__ Tb, float* __restrict__ g)
{
  int n = blockIdx.x, d = threadIdx.x;
  int qb = off[n], qe = off[n+1];
  float acc = 0.f;
  for (int q = qb; q < qe; ++q) {
    int e = elist[q];
    int s = ei[e];
    float4 p = *reinterpret_cast<const float4*>(&sc[e*4]);
    const unsigned short* Tr = Tb + (size_t)s*512;
    acc += p.x*b2f(Tr[d]) + p.y*b2f(Tr[128+d]) + p.z*b2f(Tr[256+d]) + p.w*b2f(Tr[384+d]);
  }
  g[(size_t)n*128 + d] = acc;
}

// ---------------- final: skip1 GEMV + combine + LN2 ----------------
__global__ __launch_bounds__(128) void k_final(const float* __restrict__ g1, const float* __restrict__ aux,
                       const float* __restrict__ sw, const float* __restrict__ sb,
                       const float* __restrict__ lg2, const float* __restrict__ lb2,
                       float* __restrict__ out)
{
  int row = blockIdx.x, c = threadIdx.x;
  __shared__ float gr[128];
  float gv = g1[(size_t)row*128 + c];
  gr[c] = gv; __syncthreads();
  float s1 = sb[c];
  #pragma unroll 8
  for (int k=0;k<128;++k) s1 += gr[k]*sw[k*128 + c];
  float s0 = aux[(size_t)row*128 + c];
  float v = gv + 0.5f*(s0 + s1);
  float m1 = v, m2 = v*v;
  #pragma unroll
  for (int o1=32;o1;o1>>=1){ m1 += __shfl_down(m1,o1); m2 += __shfl_down(m2,o1); }
  __shared__ float a1[2], a2[2];
  if ((c&63)==0){ a1[c>>6]=m1; a2[c>>6]=m2; }
  __syncthreads();
  float S1 = a1[0]+a1[1], S2 = a2[0]+a2[1];
  float mean = S1*(1.f/128.f), var = S2*(1.f/128.f) - mean*mean;
  out[(size_t)row*128 + c] = (v-mean)*rsqrtf(var+1e-5f)*lg2[c] + lb2[c];
}

// ---------------- host launch ----------------
extern "C" void kernel_launch(void* const* d_in, const int* in_sizes, int n_in,
                              void* d_out, int out_size, void* d_ws, size_t ws_size,
                              hipStream_t stream)
{
  const int*   ids    = (const int*)  d_in[0];
  const float* x      = (const float*)d_in[1];
  const float* ea     = (const float*)d_in[2];
  const int*   eidx   = (const int*)  d_in[3];
  const float* embed  = (const float*)d_in[4];
  const float* qkv_w  = (const float*)d_in[5];
  const float* qkv_b  = (const float*)d_in[6];
  const float* proj_w = (const float*)d_in[7];
  const float* proj_b = (const float*)d_in[8];
  const float* fuse_w = (const float*)d_in[9];
  const float* fuse_b = (const float*)d_in[10];
  const float* ln1_g  = (const float*)d_in[11];
  const float* ln1_b  = (const float*)d_in[12];
  const float* wi0 = (const float*)d_in[13]; const float* bi0 = (const float*)d_in[14];
  const float* wj0 = (const float*)d_in[15]; const float* bj0 = (const float*)d_in[16];
  const float* wt0 = (const float*)d_in[17]; const float* bt0 = (const float*)d_in[18];
  const float* attn0 = (const float*)d_in[19];
  const float* sk0w = (const float*)d_in[20]; const float* sk0b = (const float*)d_in[21];
  const float* wi1 = (const float*)d_in[22]; const float* bi1 = (const float*)d_in[23];
  const float* wj1 = (const float*)d_in[24]; const float* bj1 = (const float*)d_in[25];
  const float* wt1 = (const float*)d_in[26]; const float* bt1 = (const float*)d_in[27];
  const float* attn1 = (const float*)d_in[28];
  const float* sk1w = (const float*)d_in[29]; const float* sk1b = (const float*)d_in[30];
  const float* ln2_g = (const float*)d_in[31]; const float* ln2_b = (const float*)d_in[32];

  char* ws = (char*)d_ws;
  const size_t MBy = (size_t)1 << 20;

  // static area (0..2MB), zeroed each call
  unsigned short* BtQKV  = (unsigned short*)(ws + 0);
  unsigned short* BtW2   = (unsigned short*)(ws + 589824);   // 196608 B
  float* biasW2 = (float*)(ws + 884736);                     // 1024 B
  unsigned short* BtT0   = (unsigned short*)(ws + 1081344);  // 640x256x2
  unsigned short* BtT1   = (unsigned short*)(ws + 1409024);  // 768x128x2
  float* biasT0 = (float*)(ws + 1605632);
  float* biasT1 = (float*)(ws + 1608192);
  float* wsum   = (float*)(ws + 1611264);
  float* mxb    = (float*)(ws + 1615872);
  float* smb    = (float*)(ws + 1615936);
  int* deg    = (int*)(ws + 1703936);
  int* cursor = (int*)(ws + 1736704);
  int* off    = (int*)(ws + 1769472);
  float* cw   = (float*)(ws + 1806336);                      // 131072 B -> ends 1937408
  float* pm   = (float*)(ws + 1937408);                      // 8192 B
  float* ps   = (float*)(ws + 1945600);                      // 8192 B

  float* Ei   = (float*)(ws + 2*MBy);                   // 2..10
  unsigned short* qb = (unsigned short*)(ws + 10*MBy);  // 10..16.3
  unsigned short* kb = (unsigned short*)(ws + 17*MBy);  // 17..23.3 (row-major)
  unsigned short* vb = (unsigned short*)(ws + 24*MBy);  // 24..30.3 (fragment-order)
  unsigned short* Opart = (unsigned short*)(ws + 31*MBy);  // 31..55 (4 x 6MB bf16 partials)
  float* mpart = (float*)(ws + 55*MBy);                 // 128KB
  float* lpart = (float*)(ws + 55*MBy + 131072);        // 128KB -> ends 55.25MB
  float* pre  = (float*)(ws + 10*MBy);                  // over qb (dead after flash)
  float* emb0 = (float*)(ws + 31*MBy);                  // over Opart head (dead after mode-2)
  unsigned short* TCb0 = (unsigned short*)(ws + 39*MBy);// 39..47 (bf16 8192x512)
  float* SCb0 = (float*)(ws + 47*MBy);                  // 256KB
  float* SCb1 = (float*)(ws + 47*MBy + 262144);         // 256KB -> 47.5
  float* AUX  = (float*)(ws + 47*MBy + 524288);         // 47.5..51.5 (f32 8192x128)
  float* sc0  = (float*)(ws + 52*MBy);                  // 52..54
  float* sc1  = (float*)(ws + 54*MBy);                  // 54..56 (mpart/lpart dead by then)
  unsigned short* TCb1 = (unsigned short*)(ws + 18*MBy);// 18..26 (kb/vb dead)
  float* g0   = (float*)(ws + 2*MBy);                   // over Ei (dead after ln1)
  float* g1   = (float*)(ws + 6*MBy);                   // over Ei tail
  int* elist  = (int*)(ws + 62*MBy);                    // 62..62.5

  float* out = (float*)d_out;

  hipMemsetAsync(ws, 0, 2*MBy, stream);

  // prep: weight transforms + Ei gather + output copy (embed + ids)
  k_prep<<<16939, 256, 0, stream>>>(qkv_w, proj_w, proj_b, fuse_w, fuse_b,
                                    wt0, wt1, sk0w,
                                    wi0, bi0, wj0, bj0, wi1, bi1, wj1, bj1,
                                    attn0, attn1, bt0, bt1, sk0b, embed, ids,
                                    BtQKV, BtW2, BtT0, BtT1,
                                    biasW2, biasT0, biasT1, wsum, Ei, out);
  k_deg<<<512, 256, 0, stream>>>(eidx, deg);
  k_scan<<<1, 1024, 0, stream>>>(deg, off, cursor);
  k_fill<<<512, 256, 0, stream>>>(eidx, cursor, elist);

  // QKV GEMM with rank-1 x term, packing q(scaled)/k row-major + v fragment-order bf16
  k_gemm<<<dim3(9,64), 256, 0, stream>>>(Ei, 256, BtQKV, 256, qkv_b, nullptr, 0, 1,
                                         x, wsum, qb, kb, vb, nullptr, nullptr,
                                         nullptr, 0);
  k_flash<<<512, 256, 0, stream>>>(qb, kb, vb, Opart, mpart, lpart);
  k_cw<<<32, 256, 0, stream>>>(mpart, lpart, cw);

  // fused (combine -> att) @ (proj_w@fuse_w) + bias2  ->  pre
  k_gemm<<<dim3(2,64), 256, 0, stream>>>(nullptr, 0, BtW2, 384, biasW2, pre, 256, 2,
                                         nullptr, nullptr, nullptr, nullptr, nullptr,
                                         Opart, cw, nullptr, 0);
  k_ln1<<<8192, 256, 0, stream>>>(pre, Ei, ln1_g, ln1_b, emb0);

  // WGAT layer 0: transform -> bf16 TCb0, scores -> SCb0
  k_gemm<<<dim3(5,64), 256, 0, stream>>>(emb0, 256, BtT0, 256, biasT0, SCb0, 0, 3,
                                         nullptr, nullptr, TCb0, nullptr, nullptr,
                                         nullptr, nullptr, AUX, 520);
  k_escore<<<512, 256, 0, stream>>>(eidx, ea, SCb0, sc0, pm, ps);
  k_cfin<<<16, 128, 0, stream>>>(pm, ps, mxb, smb);
  k_pnorm<<<2048, 256, 0, stream>>>(sc0, mxb, smb);
  k_aggr<<<8192, 128, 0, stream>>>(off, elist, eidx, sc0, TCb0, g0);

  // WGAT layer 1: transform -> bf16 TCb1, scores -> SCb1, skip0 -> AUX
  k_gemm<<<dim3(6,64), 256, 0, stream>>>(g0, 128, BtT1, 128, biasT1, SCb1, 0, 3,
                                         nullptr, nullptr, TCb1, nullptr, nullptr,
                                         nullptr, nullptr, AUX, 648);
  k_escore<<<512, 256, 0, stream>>>(eidx, ea, SCb1, sc1, pm, ps);
  k_cfin<<<16, 128, 0, stream>>>(pm, ps, mxb, smb);
  k_pnorm<<<2048, 256, 0, stream>>>(sc1, mxb, smb);
  k_aggr<<<8192, 128, 0, stream>>>(off, elist, eidx, sc1, TCb1, g1);

  k_final<<<8192, 128, 0, stream>>>(g1, AUX, sk1w, sk1b, ln2_g, ln2_b, out);
}